// Round 1
// baseline (5873.954 us; speedup 1.0000x reference)
//
#include <hip/hip_runtime.h>

#define D 256

// ---------------- GEMM: C[t] = A[t] . W[t]^T (+ A2[t'] . W2[t]^T) + bias[t] ----------------
// A: (2, M, D)  W: (2, D, D) row-major [o][d]  C: (2, M, D)
// A2 optionally row-scaled by rs2 (per-row inverse counts) and track-swapped.
__global__ __launch_bounds__(256) void gemm_nt_kernel(
    const float* __restrict__ A, const float* __restrict__ W,
    const float* __restrict__ A2, const float* __restrict__ W2,
    const float* __restrict__ rs2, const float* __restrict__ bias,
    float* __restrict__ C, int M, int swap2)
{
    const int t  = blockIdx.z;
    const int m0 = blockIdx.x * 64;
    const int n0 = blockIdx.y * 64;
    const int tid = threadIdx.x;
    const int lr = tid >> 2;          // 0..63 tile row for loads
    const int lc = (tid & 3) * 4;     // 0,4,8,12 k-offset for loads
    const int tm = (tid >> 4) * 4;    // compute row group
    const int tn = (tid & 15) * 4;    // compute col group

    __shared__ float As[64][20];
    __shared__ float Bs[64][20];
    float acc[4][4] = {{0.f,0.f,0.f,0.f},{0.f,0.f,0.f,0.f},{0.f,0.f,0.f,0.f},{0.f,0.f,0.f,0.f}};

    const int npass = A2 ? 2 : 1;
    for (int pass = 0; pass < npass; ++pass) {
        const float* Ap;
        const float* Wp;
        const float* rs = nullptr;
        if (pass == 0) {
            Ap = A + (size_t)t * M * D;
            Wp = W + (size_t)t * D * D;
        } else {
            const int t2 = swap2 ? (1 - t) : t;
            Ap = A2 + (size_t)t2 * M * D;
            Wp = W2 + (size_t)t * D * D;
            if (rs2) rs = rs2 + (size_t)t2 * M;
        }
        for (int kt = 0; kt < D; kt += 16) {
            const int ra = m0 + lr;
            float4 av = make_float4(0.f, 0.f, 0.f, 0.f);
            if (ra < M) {
                av = *reinterpret_cast<const float4*>(Ap + (size_t)ra * D + kt + lc);
                if (rs) { const float s = rs[ra]; av.x *= s; av.y *= s; av.z *= s; av.w *= s; }
            }
            As[lr][lc+0] = av.x; As[lr][lc+1] = av.y; As[lr][lc+2] = av.z; As[lr][lc+3] = av.w;
            const int rb = n0 + lr;
            const float4 bv = *reinterpret_cast<const float4*>(Wp + (size_t)rb * D + kt + lc);
            Bs[lr][lc+0] = bv.x; Bs[lr][lc+1] = bv.y; Bs[lr][lc+2] = bv.z; Bs[lr][lc+3] = bv.w;
            __syncthreads();
            #pragma unroll
            for (int k = 0; k < 16; ++k) {
                const float a0 = As[tm+0][k], a1 = As[tm+1][k], a2 = As[tm+2][k], a3 = As[tm+3][k];
                const float b0 = Bs[tn+0][k], b1 = Bs[tn+1][k], b2 = Bs[tn+2][k], b3 = Bs[tn+3][k];
                acc[0][0] += a0*b0; acc[0][1] += a0*b1; acc[0][2] += a0*b2; acc[0][3] += a0*b3;
                acc[1][0] += a1*b0; acc[1][1] += a1*b1; acc[1][2] += a1*b2; acc[1][3] += a1*b3;
                acc[2][0] += a2*b0; acc[2][1] += a2*b1; acc[2][2] += a2*b2; acc[2][3] += a2*b3;
                acc[3][0] += a3*b0; acc[3][1] += a3*b1; acc[3][2] += a3*b2; acc[3][3] += a3*b3;
            }
            __syncthreads();
        }
    }
    float4 bv4 = make_float4(0.f, 0.f, 0.f, 0.f);
    if (bias) bv4 = *reinterpret_cast<const float4*>(bias + (size_t)t * D + n0 + tn);
    float* Ct = C + (size_t)t * M * D;
    #pragma unroll
    for (int i = 0; i < 4; ++i) {
        const int r = m0 + tm + i;
        if (r < M) {
            float4 o;
            o.x = acc[i][0] + bv4.x; o.y = acc[i][1] + bv4.y;
            o.z = acc[i][2] + bv4.z; o.w = acc[i][3] + bv4.w;
            *reinterpret_cast<float4*>(Ct + (size_t)r * D + n0 + tn) = o;
        }
    }
}

// ---------------- xa[t,n,r] = sum_d x[t,n,d] * lora_A[t,r,d] ----------------
__global__ __launch_bounds__(256) void xa_kernel(
    const float* __restrict__ x, const float* __restrict__ loraA,
    float* __restrict__ xa, int N)
{
    const int t  = blockIdx.z;
    const int n0 = blockIdx.x * 16;
    const int tid = threadIdx.x;
    __shared__ float xs[16][260];
    for (int i = 0; i < 16; ++i) {
        const int n = n0 + i;
        xs[i][tid] = (n < N) ? x[((size_t)t * N + n) * D + tid] : 0.f;
    }
    __syncthreads();
    const int ln = tid >> 4, r = tid & 15;
    const float* ar = loraA + ((size_t)t * 16 + r) * D;
    float acc = 0.f;
    #pragma unroll 8
    for (int d = 0; d < D; ++d) acc += xs[ln][d] * ar[d];
    const int n = n0 + ln;
    if (n < N) xa[((size_t)t * N + n) * 16 + r] = acc;
}

// ---------------- LayerNorm (+ optional LoRA add, + optional residual) ----------------
__global__ __launch_bounds__(256) void ln_kernel(
    const float* __restrict__ in, const float* __restrict__ xa,
    const float* __restrict__ loraB, const float* __restrict__ res,
    const float* __restrict__ g, const float* __restrict__ b,
    float* __restrict__ out, int N)
{
    const int t = blockIdx.z, n = blockIdx.x, o = threadIdx.x;
    const size_t idx = ((size_t)t * N + n) * D + o;
    float v = in[idx];
    __shared__ float sxa[16];
    if (xa) {
        if (o < 16) sxa[o] = xa[((size_t)t * N + n) * 16 + o];
        __syncthreads();
        const float* lb = loraB + (size_t)t * D * 16 + (size_t)o * 16;
        float ad = 0.f;
        #pragma unroll
        for (int r = 0; r < 16; ++r) ad += sxa[r] * lb[r];
        v += ad;
    }
    if (res) v += res[idx];

    __shared__ float sred[4];
    float s = v;
    #pragma unroll
    for (int off = 32; off > 0; off >>= 1) s += __shfl_down(s, off);
    if ((o & 63) == 0) sred[o >> 6] = s;
    __syncthreads();
    const float mu = (sred[0] + sred[1] + sred[2] + sred[3]) * (1.0f / 256.0f);
    __syncthreads();
    const float d = v - mu;
    s = d * d;
    #pragma unroll
    for (int off = 32; off > 0; off >>= 1) s += __shfl_down(s, off);
    if ((o & 63) == 0) sred[o >> 6] = s;
    __syncthreads();
    const float var = (sred[0] + sred[1] + sred[2] + sred[3]) * (1.0f / 256.0f);
    out[idx] = d * rsqrtf(var + 1e-5f) * g[t * D + o] + b[t * D + o];
}

// ---------------- edge count (segment counts) ----------------
__global__ void count_kernel(const int* __restrict__ e_dst, float* __restrict__ cnts,
                             int E2, int N, int E)
{
    const int i = blockIdx.x * 256 + threadIdx.x;
    if (i >= E2) return;
    const int t = i / E;
    atomicAdd(&cnts[(size_t)t * N + e_dst[i]], 1.0f);
}

__global__ void inv_kernel(float* __restrict__ cnts, int n)
{
    const int i = blockIdx.x * 256 + threadIdx.x;
    if (i < n) cnts[i] = 1.0f / fmaxf(cnts[i], 1.0f);
}

// ---------------- scatter-add of h rows into agg rows ----------------
__global__ __launch_bounds__(256) void scatter_kernel(
    const float* __restrict__ h, const int* __restrict__ e_src,
    const int* __restrict__ e_dst, float* __restrict__ agg, int N, int E)
{
    const int t = blockIdx.z;
    const int e = blockIdx.x;
    const int o = threadIdx.x;
    const int src = e_src[(size_t)t * E + e];
    const int dst = e_dst[(size_t)t * E + e];
    const float v = h[((size_t)t * N + src) * D + o];
    atomicAdd(&agg[((size_t)t * N + dst) * D + o], v);
}

// ---------------- scores: out[k] = dot(h[0][src], h[1][dst]) ----------------
__global__ __launch_bounds__(256) void score_kernel(
    const float* __restrict__ h,
    const int* __restrict__ pos_src, const int* __restrict__ pos_dst,
    const int* __restrict__ neg_src, const int* __restrict__ neg_dst,
    float* __restrict__ out, int EP, int N)
{
    const int wid  = (blockIdx.x * 256 + threadIdx.x) >> 6;
    const int lane = threadIdx.x & 63;
    if (wid >= 2 * EP) return;
    const int kind = wid / EP;
    const int k    = wid - kind * EP;
    const int s = kind ? neg_src[k] : pos_src[k];
    const int d = kind ? neg_dst[k] : pos_dst[k];
    const float4 a = *reinterpret_cast<const float4*>(h + (size_t)s * D + lane * 4);
    const float4 b = *reinterpret_cast<const float4*>(h + ((size_t)N + d) * D + lane * 4);
    float v = a.x * b.x + a.y * b.y + a.z * b.z + a.w * b.w;
    #pragma unroll
    for (int off = 32; off > 0; off >>= 1) v += __shfl_down(v, off);
    if (lane == 0) out[wid] = v;
}

extern "C" void kernel_launch(void* const* d_in, const int* in_sizes, int n_in,
                              void* d_out, int out_size, void* d_ws, size_t ws_size,
                              hipStream_t stream)
{
    const float* x      = (const float*)d_in[0];
    const float* W_in   = (const float*)d_in[1];
    const float* b_in   = (const float*)d_in[2];
    const float* lora_A = (const float*)d_in[3];
    const float* lora_B = (const float*)d_in[4];
    const float* pn_g   = (const float*)d_in[5];
    const float* pn_b   = (const float*)d_in[6];
    const float* W_self = (const float*)d_in[7];
    const float* W_neigh= (const float*)d_in[8];
    const float* b_sage = (const float*)d_in[9];
    const float* ln_g   = (const float*)d_in[10];
    const float* ln_b   = (const float*)d_in[11];
    const float* Wv     = (const float*)d_in[12];
    const float* bvp    = (const float*)d_in[13];
    const float* Wo     = (const float*)d_in[14];
    const float* bo     = (const float*)d_in[15];
    const int* e_src    = (const int*)d_in[16];
    const int* e_dst    = (const int*)d_in[17];
    const int* pos_src  = (const int*)d_in[18];
    const int* pos_dst  = (const int*)d_in[19];
    const int* neg_src  = (const int*)d_in[20];
    const int* neg_dst  = (const int*)d_in[21];

    const int N  = in_sizes[0] / (2 * D);
    const int E  = in_sizes[16] / 2;
    const int EP = in_sizes[18];

    float* ws   = (float*)d_ws;
    float* h    = ws;                       // 2*N*D
    float* tmp  = h   + (size_t)2 * N * D;  // 2*N*D
    float* agg  = tmp + (size_t)2 * N * D;  // 2*N*D
    float* xa   = agg + (size_t)2 * N * D;  // 2*N*16
    float* cnts = xa  + (size_t)2 * N * 16; // 2*N

    const dim3 gblk(256);
    const dim3 ggrid((N + 63) / 64, D / 64, 2);

    // counts (shared by both layers: edges are reused)
    hipMemsetAsync(cnts, 0, (size_t)2 * N * sizeof(float), stream);
    count_kernel<<<(2 * E + 255) / 256, 256, 0, stream>>>(e_dst, cnts, 2 * E, N, E);
    inv_kernel<<<(2 * N + 255) / 256, 256, 0, stream>>>(cnts, 2 * N);

    // LoRA projection xa = x . lora_A^T
    xa_kernel<<<dim3((N + 15) / 16, 1, 2), gblk, 0, stream>>>(x, lora_A, xa, N);

    // base = x . W_in^T + b_in ; h = LN(base + xa . lora_B^T)
    gemm_nt_kernel<<<ggrid, gblk, 0, stream>>>(x, W_in, nullptr, nullptr, nullptr, b_in, tmp, N, 0);
    ln_kernel<<<dim3(N, 1, 2), gblk, 0, stream>>>(tmp, xa, lora_B, nullptr, pn_g, pn_b, h, N);

    for (int l = 0; l < 2; ++l) {
        hipMemsetAsync(agg, 0, (size_t)2 * N * D * sizeof(float), stream);
        scatter_kernel<<<dim3(E, 1, 2), gblk, 0, stream>>>(h, e_src, e_dst, agg, N, E);
        // tmp[t] = h[t].W_self^T + (agg[1-t] * invcnt[1-t]).W_neigh^T + b_sage
        gemm_nt_kernel<<<ggrid, gblk, 0, stream>>>(h, W_self + (size_t)l * 2 * D * D,
                                                   agg, W_neigh + (size_t)l * 2 * D * D,
                                                   cnts, b_sage + (size_t)l * 2 * D, tmp, N, 1);
        if (l == 1) {
            // v = tmp.Wv^T + bv (into agg); tmp = v.Wo^T + bo; h = LN(tmp + h)
            gemm_nt_kernel<<<ggrid, gblk, 0, stream>>>(tmp, Wv, nullptr, nullptr, nullptr, bvp, agg, N, 0);
            gemm_nt_kernel<<<ggrid, gblk, 0, stream>>>(agg, Wo, nullptr, nullptr, nullptr, bo, tmp, N, 0);
            ln_kernel<<<dim3(N, 1, 2), gblk, 0, stream>>>(tmp, nullptr, nullptr, h,
                                                          ln_g + (size_t)l * 2 * D,
                                                          ln_b + (size_t)l * 2 * D, h, N);
        } else {
            ln_kernel<<<dim3(N, 1, 2), gblk, 0, stream>>>(tmp, nullptr, nullptr, nullptr,
                                                          ln_g + (size_t)l * 2 * D,
                                                          ln_b + (size_t)l * 2 * D, h, N);
        }
    }

    score_kernel<<<(2 * EP + 3) / 4, gblk, 0, stream>>>(h, pos_src, pos_dst, neg_src, neg_dst,
                                                        (float*)d_out, EP, N);
}

// Round 2
// 5194.984 us; speedup vs baseline: 1.1307x; 1.1307x over previous
//
#include <hip/hip_runtime.h>

#define D 256
#define BM 128
#define BN 128
#define BK 64

typedef __attribute__((ext_vector_type(8))) short bf16x8;
typedef __attribute__((ext_vector_type(4))) float f32x4;
typedef __attribute__((ext_vector_type(4))) unsigned int u32x4;

union frag_cvt { u32x4 u; bf16x8 h; };

// ---------------- fp32 -> bf16 (round-to-nearest-even) ----------------
__global__ void f32_to_bf16_rn_kernel(const float* __restrict__ s,
                                      unsigned short* __restrict__ d, int n)
{
    const int i = blockIdx.x * 256 + threadIdx.x;
    if (i < n) {
        const unsigned int u = __float_as_uint(s[i]);
        d[i] = (unsigned short)((u + 0x7FFFu + ((u >> 16) & 1u)) >> 16);
    }
}

// ---------------- MFMA GEMM: C[t] = A[t].W[t]^T (+ A2[t'].W2[t]^T) + bias ----------------
// A fp32 split on the fly into hi/lo bf16 planes (2-term compensated product).
// W pre-converted to bf16 (RN). A2 optionally row-scaled by rs2 and track-swapped.
__global__ __launch_bounds__(256) void gemm_mfma_kernel(
    const float* __restrict__ A, const unsigned short* __restrict__ Wb,
    const float* __restrict__ A2, const unsigned short* __restrict__ W2b,
    const float* __restrict__ rs2, const float* __restrict__ bias,
    float* __restrict__ C, int M, int swap2)
{
    const int t   = blockIdx.z;
    const int m0  = blockIdx.x * BM;
    const int n0  = blockIdx.y * BN;
    const int tid = threadIdx.x;
    const int lane = tid & 63;
    const int wid  = tid >> 6;
    const int wm = (wid >> 1) * 64;
    const int wn = (wid & 1) * 64;

    __shared__ unsigned short Ah[BM * BK];
    __shared__ unsigned short Al[BM * BK];
    __shared__ unsigned short Bs[BN * BK];
    char* AhB = (char*)Ah;
    char* AlB = (char*)Al;
    char* BsB = (char*)Bs;

    f32x4 acc[4][4];
    #pragma unroll
    for (int i = 0; i < 4; ++i)
        #pragma unroll
        for (int j = 0; j < 4; ++j)
            acc[i][j] = (f32x4){0.f, 0.f, 0.f, 0.f};

    const int npass = A2 ? 2 : 1;
    for (int pass = 0; pass < npass; ++pass) {
        const float* Ap;
        const unsigned short* Wp;
        const float* rs = nullptr;
        if (pass == 0) {
            Ap = A + (size_t)t * M * D;
            Wp = Wb + (size_t)t * D * D;
        } else {
            const int t2 = swap2 ? (1 - t) : t;
            Ap = A2 + (size_t)t2 * M * D;
            Wp = W2b + (size_t)t * D * D;
            if (rs2) rs = rs2 + (size_t)t2 * M;
        }

        for (int kt = 0; kt < D; kt += BK) {
            // ---- stage A: fp32 -> (hi trunc, lo = exact remainder) bf16, swizzled ----
            #pragma unroll
            for (int it = 0; it < 4; ++it) {
                const int g   = tid + it * 256;   // 0..1023
                const int row = g >> 3;           // 0..127
                const int kg  = g & 7;            // 8-elem group along K
                float v[8];
                const int ar = m0 + row;
                if (ar < M) {
                    const float4 p0 = *(const float4*)(Ap + (size_t)ar * D + kt + kg * 8);
                    const float4 p1 = *(const float4*)(Ap + (size_t)ar * D + kt + kg * 8 + 4);
                    v[0] = p0.x; v[1] = p0.y; v[2] = p0.z; v[3] = p0.w;
                    v[4] = p1.x; v[5] = p1.y; v[6] = p1.z; v[7] = p1.w;
                    if (rs) {
                        const float sc = rs[ar];
                        #pragma unroll
                        for (int j = 0; j < 8; ++j) v[j] *= sc;
                    }
                } else {
                    #pragma unroll
                    for (int j = 0; j < 8; ++j) v[j] = 0.f;
                }
                unsigned int hi[4], lo[4];
                #pragma unroll
                for (int j = 0; j < 4; ++j) {
                    const unsigned int ua = __float_as_uint(v[2*j]);
                    const unsigned int ub = __float_as_uint(v[2*j+1]);
                    hi[j] = (ub & 0xFFFF0000u) | (ua >> 16);
                    const float ra = v[2*j]   - __uint_as_float(ua & 0xFFFF0000u);
                    const float rb = v[2*j+1] - __uint_as_float(ub & 0xFFFF0000u);
                    lo[j] = (__float_as_uint(rb) & 0xFFFF0000u) | (__float_as_uint(ra) >> 16);
                }
                const int off = (row * BK + kg * 8) * 2;
                const int sw  = off ^ ((row & 7) << 4);
                *(u32x4*)(AhB + sw) = (u32x4){hi[0], hi[1], hi[2], hi[3]};
                *(u32x4*)(AlB + sw) = (u32x4){lo[0], lo[1], lo[2], lo[3]};
            }
            // ---- stage B: bf16 copy, swizzled ----
            #pragma unroll
            for (int it = 0; it < 4; ++it) {
                const int g   = tid + it * 256;
                const int row = g >> 3;
                const int kg  = g & 7;
                const u32x4 wv = *(const u32x4*)(Wp + (size_t)(n0 + row) * D + kt + kg * 8);
                const int off = (row * BK + kg * 8) * 2;
                const int sw  = off ^ ((row & 7) << 4);
                *(u32x4*)(BsB + sw) = wv;
            }
            __syncthreads();
            // ---- compute: 2 k32 steps, 2-term split ----
            #pragma unroll
            for (int ks = 0; ks < 2; ++ks) {
                const int kb = ks * 64 + (lane >> 4) * 16;  // byte offset within row
                bf16x8 af[4], alf[4], bfr[4];
                #pragma unroll
                for (int m = 0; m < 4; ++m) {
                    const int row = wm + m * 16 + (lane & 15);
                    const int sw  = (row * 128 + kb) ^ ((row & 7) << 4);
                    frag_cvt c1; c1.u = *(u32x4*)(AhB + sw); af[m]  = c1.h;
                    frag_cvt c2; c2.u = *(u32x4*)(AlB + sw); alf[m] = c2.h;
                }
                #pragma unroll
                for (int n = 0; n < 4; ++n) {
                    const int row = wn + n * 16 + (lane & 15);
                    const int sw  = (row * 128 + kb) ^ ((row & 7) << 4);
                    frag_cvt c; c.u = *(u32x4*)(BsB + sw); bfr[n] = c.h;
                }
                #pragma unroll
                for (int m = 0; m < 4; ++m)
                    #pragma unroll
                    for (int n = 0; n < 4; ++n) {
                        acc[m][n] = __builtin_amdgcn_mfma_f32_16x16x32_bf16(af[m],  bfr[n], acc[m][n], 0, 0, 0);
                        acc[m][n] = __builtin_amdgcn_mfma_f32_16x16x32_bf16(alf[m], bfr[n], acc[m][n], 0, 0, 0);
                    }
            }
            __syncthreads();
        }
    }
    // ---- epilogue: bias + store ----
    float* Ct = C + (size_t)t * M * D;
    #pragma unroll
    for (int n = 0; n < 4; ++n) {
        const int col = n0 + wn + n * 16 + (lane & 15);
        const float bc = bias ? bias[t * D + col] : 0.f;
        #pragma unroll
        for (int m = 0; m < 4; ++m) {
            const int rb = m0 + wm + m * 16 + (lane >> 4) * 4;
            #pragma unroll
            for (int i = 0; i < 4; ++i) {
                const int r = rb + i;
                if (r < M) Ct[(size_t)r * D + col] = acc[m][n][i] + bc;
            }
        }
    }
}

// ---------------- xa[t,n,r] = sum_d x[t,n,d] * lora_A[t,r,d] ----------------
__global__ __launch_bounds__(256) void xa_kernel(
    const float* __restrict__ x, const float* __restrict__ loraA,
    float* __restrict__ xa, int N)
{
    const int t  = blockIdx.z;
    const int n0 = blockIdx.x * 16;
    const int tid = threadIdx.x;
    __shared__ float xs[16][260];
    for (int i = 0; i < 16; ++i) {
        const int n = n0 + i;
        xs[i][tid] = (n < N) ? x[((size_t)t * N + n) * D + tid] : 0.f;
    }
    __syncthreads();
    const int ln = tid >> 4, r = tid & 15;
    const float* ar = loraA + ((size_t)t * 16 + r) * D;
    float acc = 0.f;
    #pragma unroll 8
    for (int d = 0; d < D; ++d) acc += xs[ln][d] * ar[d];
    const int n = n0 + ln;
    if (n < N) xa[((size_t)t * N + n) * 16 + r] = acc;
}

// ---------------- LayerNorm (+ optional LoRA add, + optional residual) ----------------
__global__ __launch_bounds__(256) void ln_kernel(
    const float* __restrict__ in, const float* __restrict__ xa,
    const float* __restrict__ loraB, const float* __restrict__ res,
    const float* __restrict__ g, const float* __restrict__ b,
    float* __restrict__ out, int N)
{
    const int t = blockIdx.z, n = blockIdx.x, o = threadIdx.x;
    const size_t idx = ((size_t)t * N + n) * D + o;
    float v = in[idx];
    __shared__ float sxa[16];
    if (xa) {
        if (o < 16) sxa[o] = xa[((size_t)t * N + n) * 16 + o];
        __syncthreads();
        const float* lb = loraB + (size_t)t * D * 16 + (size_t)o * 16;
        float ad = 0.f;
        #pragma unroll
        for (int r = 0; r < 16; ++r) ad += sxa[r] * lb[r];
        v += ad;
    }
    if (res) v += res[idx];

    __shared__ float sred[4];
    float s = v;
    #pragma unroll
    for (int off = 32; off > 0; off >>= 1) s += __shfl_down(s, off);
    if ((o & 63) == 0) sred[o >> 6] = s;
    __syncthreads();
    const float mu = (sred[0] + sred[1] + sred[2] + sred[3]) * (1.0f / 256.0f);
    __syncthreads();
    const float d = v - mu;
    s = d * d;
    #pragma unroll
    for (int off = 32; off > 0; off >>= 1) s += __shfl_down(s, off);
    if ((o & 63) == 0) sred[o >> 6] = s;
    __syncthreads();
    const float var = (sred[0] + sred[1] + sred[2] + sred[3]) * (1.0f / 256.0f);
    out[idx] = d * rsqrtf(var + 1e-5f) * g[t * D + o] + b[t * D + o];
}

// ---------------- edge counts ----------------
__global__ void count_kernel(const int* __restrict__ e_dst, float* __restrict__ cnts,
                             int E2, int N, int E)
{
    const int i = blockIdx.x * 256 + threadIdx.x;
    if (i >= E2) return;
    const int t = i / E;
    atomicAdd(&cnts[(size_t)t * N + e_dst[i]], 1.0f);
}

__global__ void inv_kernel(float* __restrict__ cnts, int n)
{
    const int i = blockIdx.x * 256 + threadIdx.x;
    if (i < n) cnts[i] = 1.0f / fmaxf(cnts[i], 1.0f);
}

// ---------------- scatter-add: one wave per edge ----------------
__global__ __launch_bounds__(256) void scatter_kernel(
    const float* __restrict__ h, const int* __restrict__ e_src,
    const int* __restrict__ e_dst, float* __restrict__ agg, int N, int E)
{
    const int gw   = (blockIdx.x * 256 + threadIdx.x) >> 6;
    const int lane = threadIdx.x & 63;
    if (gw >= 2 * E) return;
    const int t = gw / E;
    const int e = gw - t * E;
    const int src = e_src[(size_t)t * E + e];
    const int dst = e_dst[(size_t)t * E + e];
    const float4 v = *(const float4*)(h + ((size_t)t * N + src) * D + lane * 4);
    float* dp = agg + ((size_t)t * N + dst) * D + lane * 4;
    atomicAdd(dp + 0, v.x);
    atomicAdd(dp + 1, v.y);
    atomicAdd(dp + 2, v.z);
    atomicAdd(dp + 3, v.w);
}

// ---------------- scores ----------------
__global__ __launch_bounds__(256) void score_kernel(
    const float* __restrict__ h,
    const int* __restrict__ pos_src, const int* __restrict__ pos_dst,
    const int* __restrict__ neg_src, const int* __restrict__ neg_dst,
    float* __restrict__ out, int EP, int N)
{
    const int wid  = (blockIdx.x * 256 + threadIdx.x) >> 6;
    const int lane = threadIdx.x & 63;
    if (wid >= 2 * EP) return;
    const int kind = wid / EP;
    const int k    = wid - kind * EP;
    const int s = kind ? neg_src[k] : pos_src[k];
    const int d = kind ? neg_dst[k] : pos_dst[k];
    const float4 a = *reinterpret_cast<const float4*>(h + (size_t)s * D + lane * 4);
    const float4 b = *reinterpret_cast<const float4*>(h + ((size_t)N + d) * D + lane * 4);
    float v = a.x * b.x + a.y * b.y + a.z * b.z + a.w * b.w;
    #pragma unroll
    for (int off = 32; off > 0; off >>= 1) v += __shfl_down(v, off);
    if (lane == 0) out[wid] = v;
}

extern "C" void kernel_launch(void* const* d_in, const int* in_sizes, int n_in,
                              void* d_out, int out_size, void* d_ws, size_t ws_size,
                              hipStream_t stream)
{
    const float* x      = (const float*)d_in[0];
    const float* W_in   = (const float*)d_in[1];
    const float* b_in   = (const float*)d_in[2];
    const float* lora_A = (const float*)d_in[3];
    const float* lora_B = (const float*)d_in[4];
    const float* pn_g   = (const float*)d_in[5];
    const float* pn_b   = (const float*)d_in[6];
    const float* W_self = (const float*)d_in[7];
    const float* W_neigh= (const float*)d_in[8];
    const float* b_sage = (const float*)d_in[9];
    const float* ln_g   = (const float*)d_in[10];
    const float* ln_b   = (const float*)d_in[11];
    const float* Wv     = (const float*)d_in[12];
    const float* bvp    = (const float*)d_in[13];
    const float* Wo     = (const float*)d_in[14];
    const float* bo     = (const float*)d_in[15];
    const int* e_src    = (const int*)d_in[16];
    const int* e_dst    = (const int*)d_in[17];
    const int* pos_src  = (const int*)d_in[18];
    const int* pos_dst  = (const int*)d_in[19];
    const int* neg_src  = (const int*)d_in[20];
    const int* neg_dst  = (const int*)d_in[21];

    const int N  = in_sizes[0] / (2 * D);
    const int E  = in_sizes[16] / 2;
    const int EP = in_sizes[18];

    float* ws   = (float*)d_ws;
    float* h    = ws;                       // 2*N*D
    float* tmp  = h   + (size_t)2 * N * D;  // 2*N*D
    float* agg  = tmp + (size_t)2 * N * D;  // 2*N*D
    float* xa   = agg + (size_t)2 * N * D;  // 2*N*16
    float* cnts = xa  + (size_t)2 * N * 16; // 2*N
    unsigned short* wbf = (unsigned short*)(cnts + (size_t)2 * N);
    unsigned short* win_bf    = wbf;                       // 2*D*D
    unsigned short* wself_bf  = win_bf   + 2 * D * D;      // 4*D*D
    unsigned short* wneigh_bf = wself_bf + 4 * D * D;      // 4*D*D
    unsigned short* wv_bf     = wneigh_bf+ 4 * D * D;      // 2*D*D
    unsigned short* wo_bf     = wv_bf    + 2 * D * D;      // 2*D*D

    // pre-convert weights to bf16 (RN)
    f32_to_bf16_rn_kernel<<<(2*D*D + 255) / 256, 256, 0, stream>>>(W_in,    win_bf,    2*D*D);
    f32_to_bf16_rn_kernel<<<(4*D*D + 255) / 256, 256, 0, stream>>>(W_self,  wself_bf,  4*D*D);
    f32_to_bf16_rn_kernel<<<(4*D*D + 255) / 256, 256, 0, stream>>>(W_neigh, wneigh_bf, 4*D*D);
    f32_to_bf16_rn_kernel<<<(2*D*D + 255) / 256, 256, 0, stream>>>(Wv,      wv_bf,     2*D*D);
    f32_to_bf16_rn_kernel<<<(2*D*D + 255) / 256, 256, 0, stream>>>(Wo,      wo_bf,     2*D*D);

    const dim3 gblk(256);
    const dim3 ggrid((N + BM - 1) / BM, D / BN, 2);

    // counts (edges shared by both layers)
    hipMemsetAsync(cnts, 0, (size_t)2 * N * sizeof(float), stream);
    count_kernel<<<(2 * E + 255) / 256, 256, 0, stream>>>(e_dst, cnts, 2 * E, N, E);
    inv_kernel<<<(2 * N + 255) / 256, 256, 0, stream>>>(cnts, 2 * N);

    // LoRA projection
    xa_kernel<<<dim3((N + 15) / 16, 1, 2), gblk, 0, stream>>>(x, lora_A, xa, N);

    // input projection + prenorm
    gemm_mfma_kernel<<<ggrid, gblk, 0, stream>>>(x, win_bf, nullptr, nullptr, nullptr, b_in, tmp, N, 0);
    ln_kernel<<<dim3(N, 1, 2), gblk, 0, stream>>>(tmp, xa, lora_B, nullptr, pn_g, pn_b, h, N);

    for (int l = 0; l < 2; ++l) {
        hipMemsetAsync(agg, 0, (size_t)2 * N * D * sizeof(float), stream);
        scatter_kernel<<<dim3((2 * E + 3) / 4, 1, 1), gblk, 0, stream>>>(h, e_src, e_dst, agg, N, E);
        gemm_mfma_kernel<<<ggrid, gblk, 0, stream>>>(h, wself_bf + (size_t)l * 2 * D * D,
                                                     agg, wneigh_bf + (size_t)l * 2 * D * D,
                                                     cnts, b_sage + (size_t)l * 2 * D, tmp, N, 1);
        if (l == 1) {
            gemm_mfma_kernel<<<ggrid, gblk, 0, stream>>>(tmp, wv_bf, nullptr, nullptr, nullptr, bvp, agg, N, 0);
            gemm_mfma_kernel<<<ggrid, gblk, 0, stream>>>(agg, wo_bf, nullptr, nullptr, nullptr, bo, tmp, N, 0);
            ln_kernel<<<dim3(N, 1, 2), gblk, 0, stream>>>(tmp, nullptr, nullptr, h,
                                                          ln_g + (size_t)l * 2 * D,
                                                          ln_b + (size_t)l * 2 * D, h, N);
        } else {
            ln_kernel<<<dim3(N, 1, 2), gblk, 0, stream>>>(tmp, nullptr, nullptr, nullptr,
                                                          ln_g + (size_t)l * 2 * D,
                                                          ln_b + (size_t)l * 2 * D, h, N);
        }
    }

    score_kernel<<<(2 * EP + 3) / 4, gblk, 0, stream>>>(h, pos_src, pos_dst, neg_src, neg_dst,
                                                        (float*)d_out, EP, N);
}

// Round 3
// 1468.714 us; speedup vs baseline: 3.9994x; 3.5371x over previous
//
#include <hip/hip_runtime.h>

#define D 256
#define BM 128
#define BN 128
#define BK 64

typedef __attribute__((ext_vector_type(8))) short bf16x8;
typedef __attribute__((ext_vector_type(4))) float f32x4;
typedef __attribute__((ext_vector_type(4))) unsigned int u32x4;

union frag_cvt { u32x4 u; bf16x8 h; };

// ---------------- fp32 -> bf16 (round-to-nearest-even) ----------------
__global__ void f32_to_bf16_rn_kernel(const float* __restrict__ s,
                                      unsigned short* __restrict__ d, int n)
{
    const int i = blockIdx.x * 256 + threadIdx.x;
    if (i < n) {
        const unsigned int u = __float_as_uint(s[i]);
        d[i] = (unsigned short)((u + 0x7FFFu + ((u >> 16) & 1u)) >> 16);
    }
}

// ---------------- MFMA GEMM: C[t] = A[t].W[t]^T (+ A2[t'].W2[t]^T) + bias ----------------
__global__ __launch_bounds__(256) void gemm_mfma_kernel(
    const float* __restrict__ A, const unsigned short* __restrict__ Wb,
    const float* __restrict__ A2, const unsigned short* __restrict__ W2b,
    const float* __restrict__ bias,
    float* __restrict__ C, int M, int swap2)
{
    const int t   = blockIdx.z;
    const int m0  = blockIdx.x * BM;
    const int n0  = blockIdx.y * BN;
    const int tid = threadIdx.x;
    const int lane = tid & 63;
    const int wid  = tid >> 6;
    const int wm = (wid >> 1) * 64;
    const int wn = (wid & 1) * 64;

    __shared__ unsigned short Ah[BM * BK];
    __shared__ unsigned short Al[BM * BK];
    __shared__ unsigned short Bs[BN * BK];
    char* AhB = (char*)Ah;
    char* AlB = (char*)Al;
    char* BsB = (char*)Bs;

    f32x4 acc[4][4];
    #pragma unroll
    for (int i = 0; i < 4; ++i)
        #pragma unroll
        for (int j = 0; j < 4; ++j)
            acc[i][j] = (f32x4){0.f, 0.f, 0.f, 0.f};

    const int npass = A2 ? 2 : 1;
    for (int pass = 0; pass < npass; ++pass) {
        const float* Ap;
        const unsigned short* Wp;
        if (pass == 0) {
            Ap = A + (size_t)t * M * D;
            Wp = Wb + (size_t)t * D * D;
        } else {
            const int t2 = swap2 ? (1 - t) : t;
            Ap = A2 + (size_t)t2 * M * D;
            Wp = W2b + (size_t)t * D * D;
        }

        for (int kt = 0; kt < D; kt += BK) {
            // ---- stage A: fp32 -> (hi trunc, lo = exact remainder) bf16, swizzled ----
            #pragma unroll
            for (int it = 0; it < 4; ++it) {
                const int g   = tid + it * 256;   // 0..1023
                const int row = g >> 3;           // 0..127
                const int kg  = g & 7;            // 8-elem group along K
                float v[8];
                const int ar = m0 + row;
                if (ar < M) {
                    const float4 p0 = *(const float4*)(Ap + (size_t)ar * D + kt + kg * 8);
                    const float4 p1 = *(const float4*)(Ap + (size_t)ar * D + kt + kg * 8 + 4);
                    v[0] = p0.x; v[1] = p0.y; v[2] = p0.z; v[3] = p0.w;
                    v[4] = p1.x; v[5] = p1.y; v[6] = p1.z; v[7] = p1.w;
                } else {
                    #pragma unroll
                    for (int j = 0; j < 8; ++j) v[j] = 0.f;
                }
                unsigned int hi[4], lo[4];
                #pragma unroll
                for (int j = 0; j < 4; ++j) {
                    const unsigned int ua = __float_as_uint(v[2*j]);
                    const unsigned int ub = __float_as_uint(v[2*j+1]);
                    hi[j] = (ub & 0xFFFF0000u) | (ua >> 16);
                    const float ra = v[2*j]   - __uint_as_float(ua & 0xFFFF0000u);
                    const float rb = v[2*j+1] - __uint_as_float(ub & 0xFFFF0000u);
                    lo[j] = (__float_as_uint(rb) & 0xFFFF0000u) | (__float_as_uint(ra) >> 16);
                }
                const int off = (row * BK + kg * 8) * 2;
                const int sw  = off ^ ((row & 7) << 4);
                *(u32x4*)(AhB + sw) = (u32x4){hi[0], hi[1], hi[2], hi[3]};
                *(u32x4*)(AlB + sw) = (u32x4){lo[0], lo[1], lo[2], lo[3]};
            }
            // ---- stage B: bf16 copy, swizzled ----
            #pragma unroll
            for (int it = 0; it < 4; ++it) {
                const int g   = tid + it * 256;
                const int row = g >> 3;
                const int kg  = g & 7;
                const u32x4 wv = *(const u32x4*)(Wp + (size_t)(n0 + row) * D + kt + kg * 8);
                const int off = (row * BK + kg * 8) * 2;
                const int sw  = off ^ ((row & 7) << 4);
                *(u32x4*)(BsB + sw) = wv;
            }
            __syncthreads();
            // ---- compute: 2 k32 steps, 2-term split ----
            #pragma unroll
            for (int ks = 0; ks < 2; ++ks) {
                const int kb = ks * 64 + (lane >> 4) * 16;
                bf16x8 af[4], alf[4], bfr[4];
                #pragma unroll
                for (int m = 0; m < 4; ++m) {
                    const int row = wm + m * 16 + (lane & 15);
                    const int sw  = (row * 128 + kb) ^ ((row & 7) << 4);
                    frag_cvt c1; c1.u = *(u32x4*)(AhB + sw); af[m]  = c1.h;
                    frag_cvt c2; c2.u = *(u32x4*)(AlB + sw); alf[m] = c2.h;
                }
                #pragma unroll
                for (int n = 0; n < 4; ++n) {
                    const int row = wn + n * 16 + (lane & 15);
                    const int sw  = (row * 128 + kb) ^ ((row & 7) << 4);
                    frag_cvt c; c.u = *(u32x4*)(BsB + sw); bfr[n] = c.h;
                }
                #pragma unroll
                for (int m = 0; m < 4; ++m)
                    #pragma unroll
                    for (int n = 0; n < 4; ++n) {
                        acc[m][n] = __builtin_amdgcn_mfma_f32_16x16x32_bf16(af[m],  bfr[n], acc[m][n], 0, 0, 0);
                        acc[m][n] = __builtin_amdgcn_mfma_f32_16x16x32_bf16(alf[m], bfr[n], acc[m][n], 0, 0, 0);
                    }
            }
            __syncthreads();
        }
    }
    // ---- epilogue ----
    float* Ct = C + (size_t)t * M * D;
    #pragma unroll
    for (int n = 0; n < 4; ++n) {
        const int col = n0 + wn + n * 16 + (lane & 15);
        const float bc = bias ? bias[t * D + col] : 0.f;
        #pragma unroll
        for (int m = 0; m < 4; ++m) {
            const int rb = m0 + wm + m * 16 + (lane >> 4) * 4;
            #pragma unroll
            for (int i = 0; i < 4; ++i) {
                const int r = rb + i;
                if (r < M) Ct[(size_t)r * D + col] = acc[m][n][i] + bc;
            }
        }
    }
}

// ---------------- xa[t,n,r] = sum_d x[t,n,d] * lora_A[t,r,d] ----------------
__global__ __launch_bounds__(256) void xa_kernel(
    const float* __restrict__ x, const float* __restrict__ loraA,
    float* __restrict__ xa, int N)
{
    const int t  = blockIdx.z;
    const int n0 = blockIdx.x * 16;
    const int tid = threadIdx.x;
    __shared__ float xs[16][260];
    for (int i = 0; i < 16; ++i) {
        const int n = n0 + i;
        xs[i][tid] = (n < N) ? x[((size_t)t * N + n) * D + tid] : 0.f;
    }
    __syncthreads();
    const int ln = tid >> 4, r = tid & 15;
    const float* ar = loraA + ((size_t)t * 16 + r) * D;
    float acc = 0.f;
    #pragma unroll 8
    for (int d = 0; d < D; ++d) acc += xs[ln][d] * ar[d];
    const int n = n0 + ln;
    if (n < N) xa[((size_t)t * N + n) * 16 + r] = acc;
}

// ---------------- LayerNorm (+ optional LoRA add, + optional residual) ----------------
__global__ __launch_bounds__(256) void ln_kernel(
    const float* __restrict__ in, const float* __restrict__ xa,
    const float* __restrict__ loraB, const float* __restrict__ res,
    const float* __restrict__ g, const float* __restrict__ b,
    float* __restrict__ out, int N)
{
    const int t = blockIdx.z, n = blockIdx.x, o = threadIdx.x;
    const size_t idx = ((size_t)t * N + n) * D + o;
    float v = in[idx];
    __shared__ float sxa[16];
    if (xa) {
        if (o < 16) sxa[o] = xa[((size_t)t * N + n) * 16 + o];
        __syncthreads();
        const float* lb = loraB + (size_t)t * D * 16 + (size_t)o * 16;
        float ad = 0.f;
        #pragma unroll
        for (int r = 0; r < 16; ++r) ad += sxa[r] * lb[r];
        v += ad;
    }
    if (res) v += res[idx];

    __shared__ float sred[4];
    float s = v;
    #pragma unroll
    for (int off = 32; off > 0; off >>= 1) s += __shfl_down(s, off);
    if ((o & 63) == 0) sred[o >> 6] = s;
    __syncthreads();
    const float mu = (sred[0] + sred[1] + sred[2] + sred[3]) * (1.0f / 256.0f);
    __syncthreads();
    const float d = v - mu;
    s = d * d;
    #pragma unroll
    for (int off = 32; off > 0; off >>= 1) s += __shfl_down(s, off);
    if ((o & 63) == 0) sred[o >> 6] = s;
    __syncthreads();
    const float var = (sred[0] + sred[1] + sred[2] + sred[3]) * (1.0f / 256.0f);
    out[idx] = d * rsqrtf(var + 1e-5f) * g[t * D + o] + b[t * D + o];
}

// ---------------- CSR build: count, scan, fill ----------------
__global__ void count_kernel(const int* __restrict__ e_dst, int* __restrict__ cnt,
                             int E2, int N, int E)
{
    const int i = blockIdx.x * 256 + threadIdx.x;
    if (i >= E2) return;
    const int t = i / E;
    atomicAdd(&cnt[(size_t)t * N + e_dst[i]], 1);
}

__global__ __launch_bounds__(1024) void scan_kernel(const int* __restrict__ cnt,
                                                    int* __restrict__ offs, int n)
{
    __shared__ int ts[1024];
    const int tid = threadIdx.x;
    const int chunk = (n + 1023) / 1024;
    const int b = tid * chunk;
    const int e = min(b + chunk, n);
    int s = 0;
    for (int i = b; i < e; ++i) s += cnt[i];
    ts[tid] = s;
    __syncthreads();
    for (int off = 1; off < 1024; off <<= 1) {
        const int v = (tid >= off) ? ts[tid - off] : 0;
        __syncthreads();
        ts[tid] += v;
        __syncthreads();
    }
    int base = ts[tid] - s;   // exclusive prefix of this chunk
    for (int i = b; i < e; ++i) { offs[i] = base; base += cnt[i]; }
    if (tid == 1023) offs[n] = ts[1023];
}

__global__ void fill_kernel(const int* __restrict__ e_src, const int* __restrict__ e_dst,
                            const int* __restrict__ offs, int* __restrict__ cur,
                            int* __restrict__ sorted, int E2, int N, int E)
{
    const int i = blockIdx.x * 256 + threadIdx.x;
    if (i >= E2) return;
    const int t = i / E;
    const int idx = t * N + e_dst[i];
    const int pos = offs[idx] + atomicAdd(&cur[idx], 1);
    sorted[pos] = e_src[i];
}

// ---------------- aggregation: one wave per (t, dst) node, gather + mean ----------------
__global__ __launch_bounds__(256) void agg_kernel(
    const float* __restrict__ h, const int* __restrict__ sorted_src,
    const int* __restrict__ offs, float* __restrict__ agg, int N)
{
    const int gw   = (blockIdx.x * 256 + threadIdx.x) >> 6;
    const int lane = threadIdx.x & 63;
    if (gw >= 2 * N) return;
    const int t = gw / N;
    const int beg = offs[gw];
    const int end = offs[gw + 1];
    const float* hb = h + (size_t)t * N * D;
    float4 acc = make_float4(0.f, 0.f, 0.f, 0.f);
    for (int e = beg; e < end; ++e) {
        const int src = sorted_src[e];
        const float4 v = *(const float4*)(hb + (size_t)src * D + lane * 4);
        acc.x += v.x; acc.y += v.y; acc.z += v.z; acc.w += v.w;
    }
    const float inv = 1.0f / fmaxf((float)(end - beg), 1.0f);
    acc.x *= inv; acc.y *= inv; acc.z *= inv; acc.w *= inv;
    *(float4*)(agg + (size_t)gw * D + lane * 4) = acc;
}

// ---------------- scores ----------------
__global__ __launch_bounds__(256) void score_kernel(
    const float* __restrict__ h,
    const int* __restrict__ pos_src, const int* __restrict__ pos_dst,
    const int* __restrict__ neg_src, const int* __restrict__ neg_dst,
    float* __restrict__ out, int EP, int N)
{
    const int wid  = (blockIdx.x * 256 + threadIdx.x) >> 6;
    const int lane = threadIdx.x & 63;
    if (wid >= 2 * EP) return;
    const int kind = wid / EP;
    const int k    = wid - kind * EP;
    const int s = kind ? neg_src[k] : pos_src[k];
    const int d = kind ? neg_dst[k] : pos_dst[k];
    const float4 a = *reinterpret_cast<const float4*>(h + (size_t)s * D + lane * 4);
    const float4 b = *reinterpret_cast<const float4*>(h + ((size_t)N + d) * D + lane * 4);
    float v = a.x * b.x + a.y * b.y + a.z * b.z + a.w * b.w;
    #pragma unroll
    for (int off = 32; off > 0; off >>= 1) v += __shfl_down(v, off);
    if (lane == 0) out[wid] = v;
}

extern "C" void kernel_launch(void* const* d_in, const int* in_sizes, int n_in,
                              void* d_out, int out_size, void* d_ws, size_t ws_size,
                              hipStream_t stream)
{
    const float* x      = (const float*)d_in[0];
    const float* W_in   = (const float*)d_in[1];
    const float* b_in   = (const float*)d_in[2];
    const float* lora_A = (const float*)d_in[3];
    const float* lora_B = (const float*)d_in[4];
    const float* pn_g   = (const float*)d_in[5];
    const float* pn_b   = (const float*)d_in[6];
    const float* W_self = (const float*)d_in[7];
    const float* W_neigh= (const float*)d_in[8];
    const float* b_sage = (const float*)d_in[9];
    const float* ln_g   = (const float*)d_in[10];
    const float* ln_b   = (const float*)d_in[11];
    const float* Wv     = (const float*)d_in[12];
    const float* bvp    = (const float*)d_in[13];
    const float* Wo     = (const float*)d_in[14];
    const float* bo     = (const float*)d_in[15];
    const int* e_src    = (const int*)d_in[16];
    const int* e_dst    = (const int*)d_in[17];
    const int* pos_src  = (const int*)d_in[18];
    const int* pos_dst  = (const int*)d_in[19];
    const int* neg_src  = (const int*)d_in[20];
    const int* neg_dst  = (const int*)d_in[21];

    const int N  = in_sizes[0] / (2 * D);
    const int E  = in_sizes[16] / 2;
    const int EP = in_sizes[18];

    float* ws   = (float*)d_ws;
    float* h    = ws;                       // 2*N*D
    float* tmp  = h   + (size_t)2 * N * D;  // 2*N*D
    float* agg  = tmp + (size_t)2 * N * D;  // 2*N*D
    float* xa   = agg + (size_t)2 * N * D;  // 2*N*16
    int* cnt    = (int*)(xa + (size_t)2 * N * 16);
    int* offs   = cnt  + (size_t)2 * N;     // 2*N+1
    int* cur    = offs + (size_t)2 * N + 1;
    int* sorted = cur  + (size_t)2 * N;     // 2*E
    unsigned short* wbf = (unsigned short*)(sorted + (size_t)2 * E);
    unsigned short* win_bf    = wbf;
    unsigned short* wself_bf  = win_bf   + 2 * D * D;
    unsigned short* wneigh_bf = wself_bf + 4 * D * D;
    unsigned short* wv_bf     = wneigh_bf+ 4 * D * D;
    unsigned short* wo_bf     = wv_bf    + 2 * D * D;

    // weights -> bf16 (RN)
    f32_to_bf16_rn_kernel<<<(2*D*D + 255) / 256, 256, 0, stream>>>(W_in,    win_bf,    2*D*D);
    f32_to_bf16_rn_kernel<<<(4*D*D + 255) / 256, 256, 0, stream>>>(W_self,  wself_bf,  4*D*D);
    f32_to_bf16_rn_kernel<<<(4*D*D + 255) / 256, 256, 0, stream>>>(W_neigh, wneigh_bf, 4*D*D);
    f32_to_bf16_rn_kernel<<<(2*D*D + 255) / 256, 256, 0, stream>>>(Wv,      wv_bf,     2*D*D);
    f32_to_bf16_rn_kernel<<<(2*D*D + 255) / 256, 256, 0, stream>>>(Wo,      wo_bf,     2*D*D);

    // CSR build (edges shared by both layers)
    hipMemsetAsync(cnt, 0, (size_t)2 * N * sizeof(int), stream);
    hipMemsetAsync(cur, 0, (size_t)2 * N * sizeof(int), stream);
    count_kernel<<<(2 * E + 255) / 256, 256, 0, stream>>>(e_dst, cnt, 2 * E, N, E);
    scan_kernel<<<1, 1024, 0, stream>>>(cnt, offs, 2 * N);
    fill_kernel<<<(2 * E + 255) / 256, 256, 0, stream>>>(e_src, e_dst, offs, cur, sorted, 2 * E, N, E);

    const dim3 gblk(256);
    const dim3 ggrid((N + BM - 1) / BM, D / BN, 2);

    // LoRA projection + input projection + prenorm
    xa_kernel<<<dim3((N + 15) / 16, 1, 2), gblk, 0, stream>>>(x, lora_A, xa, N);
    gemm_mfma_kernel<<<ggrid, gblk, 0, stream>>>(x, win_bf, nullptr, nullptr, b_in, tmp, N, 0);
    ln_kernel<<<dim3(N, 1, 2), gblk, 0, stream>>>(tmp, xa, lora_B, nullptr, pn_g, pn_b, h, N);

    for (int l = 0; l < 2; ++l) {
        agg_kernel<<<dim3((2 * N + 3) / 4, 1, 1), gblk, 0, stream>>>(h, sorted, offs, agg, N);
        gemm_mfma_kernel<<<ggrid, gblk, 0, stream>>>(h, wself_bf + (size_t)l * 2 * D * D,
                                                     agg, wneigh_bf + (size_t)l * 2 * D * D,
                                                     b_sage + (size_t)l * 2 * D, tmp, N, 1);
        if (l == 1) {
            gemm_mfma_kernel<<<ggrid, gblk, 0, stream>>>(tmp, wv_bf, nullptr, nullptr, bvp, agg, N, 0);
            gemm_mfma_kernel<<<ggrid, gblk, 0, stream>>>(agg, wo_bf, nullptr, nullptr, bo, tmp, N, 0);
            ln_kernel<<<dim3(N, 1, 2), gblk, 0, stream>>>(tmp, nullptr, nullptr, h,
                                                          ln_g + (size_t)l * 2 * D,
                                                          ln_b + (size_t)l * 2 * D, h, N);
        } else {
            ln_kernel<<<dim3(N, 1, 2), gblk, 0, stream>>>(tmp, nullptr, nullptr, nullptr,
                                                          ln_g + (size_t)l * 2 * D,
                                                          ln_b + (size_t)l * 2 * D, h, N);
        }
    }

    score_kernel<<<(2 * EP + 3) / 4, gblk, 0, stream>>>(h, pos_src, pos_dst, neg_src, neg_dst,
                                                        (float*)d_out, EP, N);
}

// Round 4
// 979.967 us; speedup vs baseline: 5.9940x; 1.4987x over previous
//
#include <hip/hip_runtime.h>

#define D 256
#define BM 128
#define BN 128
#define BK 64

typedef __attribute__((ext_vector_type(8))) short bf16x8;
typedef __attribute__((ext_vector_type(4))) float f32x4;
typedef __attribute__((ext_vector_type(4))) unsigned int u32x4;

union frag_cvt { u32x4 u; bf16x8 h; };

__device__ __forceinline__ unsigned short bf16_rn(float f) {
    const unsigned int u = __float_as_uint(f);
    return (unsigned short)((u + 0x7FFFu + ((u >> 16) & 1u)) >> 16);
}

// ---------------- fp32 -> bf16 (RN) ----------------
__global__ void f32_to_bf16_rn_kernel(const float* __restrict__ s,
                                      unsigned short* __restrict__ d, int n)
{
    const int i = blockIdx.x * 256 + threadIdx.x;
    if (i < n) d[i] = bf16_rn(s[i]);
}

// ---------------- W_eff = W + lora_B . lora_A  -> bf16 ----------------
// W:(2,D,D)[o][d]  lora_A:(2,16,D)[r][d]  lora_B:(2,D,16)[o][r]
__global__ __launch_bounds__(256) void lora_fold_kernel(
    const float* __restrict__ W, const float* __restrict__ lA,
    const float* __restrict__ lB, unsigned short* __restrict__ out)
{
    const int t = blockIdx.z, o = blockIdx.x, d = threadIdx.x;
    float acc = W[((size_t)t * D + o) * D + d];
    const float* Br = lB + ((size_t)t * D + o) * 16;
    const float* At = lA + (size_t)t * 16 * D;
    #pragma unroll
    for (int r = 0; r < 16; ++r) acc = fmaf(Br[r], At[r * D + d], acc);
    out[((size_t)t * D + o) * D + d] = bf16_rn(acc);
}

// ---------------- P[t,p,:] = sum_o X[t,p,o] * Y[t,o,:]  (NN matmul, D x D) ----------------
__global__ __launch_bounds__(256) void mm_nn_kernel(
    const float* __restrict__ X, const float* __restrict__ Y,
    float* __restrict__ Pf, unsigned short* __restrict__ Pb)
{
    const int t = blockIdx.z, p = blockIdx.x, d = threadIdx.x;
    const float* Xr = X + ((size_t)t * D + p) * D;
    const float* Yt = Y + (size_t)t * D * D;
    float acc = 0.f;
    for (int o = 0; o < D; ++o) acc = fmaf(Xr[o], Yt[(size_t)o * D + d], acc);
    if (Pf) Pf[((size_t)t * D + p) * D + d] = acc;
    if (Pb) Pb[((size_t)t * D + p) * D + d] = bf16_rn(acc);
}

// ---------------- out[t,p] = add[t,p] + sum_o M[t,p,o] * v[t,o] ----------------
__global__ __launch_bounds__(256) void mv_kernel(
    const float* __restrict__ M, const float* __restrict__ v,
    const float* __restrict__ add, float* __restrict__ out)
{
    const int t = blockIdx.z, p = threadIdx.x;
    const float* Mr = M + ((size_t)t * D + p) * D;
    const float* vr = v + (size_t)t * D;
    float acc = add[(size_t)t * D + p];
    for (int o = 0; o < D; ++o) acc = fmaf(Mr[o], vr[o], acc);
    out[(size_t)t * D + p] = acc;
}

// ---------------- MFMA GEMM: C[t] = A[t].W[t]^T (+ A2[t'].W2[t]^T) + bias ----------------
__global__ __launch_bounds__(256) void gemm_mfma_kernel(
    const float* __restrict__ A, const unsigned short* __restrict__ Wb,
    const float* __restrict__ A2, const unsigned short* __restrict__ W2b,
    const float* __restrict__ bias,
    float* __restrict__ C, int M, int swap2)
{
    const int t   = blockIdx.z;
    const int m0  = blockIdx.x * BM;
    const int n0  = blockIdx.y * BN;
    const int tid = threadIdx.x;
    const int lane = tid & 63;
    const int wid  = tid >> 6;
    const int wm = (wid >> 1) * 64;
    const int wn = (wid & 1) * 64;

    __shared__ unsigned short Ah[BM * BK];
    __shared__ unsigned short Al[BM * BK];
    __shared__ unsigned short Bs[BN * BK];
    char* AhB = (char*)Ah;
    char* AlB = (char*)Al;
    char* BsB = (char*)Bs;

    f32x4 acc[4][4];
    #pragma unroll
    for (int i = 0; i < 4; ++i)
        #pragma unroll
        for (int j = 0; j < 4; ++j)
            acc[i][j] = (f32x4){0.f, 0.f, 0.f, 0.f};

    const int npass = A2 ? 2 : 1;
    for (int pass = 0; pass < npass; ++pass) {
        const float* Ap;
        const unsigned short* Wp;
        if (pass == 0) {
            Ap = A + (size_t)t * M * D;
            Wp = Wb + (size_t)t * D * D;
        } else {
            const int t2 = swap2 ? (1 - t) : t;
            Ap = A2 + (size_t)t2 * M * D;
            Wp = W2b + (size_t)t * D * D;
        }

        for (int kt = 0; kt < D; kt += BK) {
            #pragma unroll
            for (int it = 0; it < 4; ++it) {
                const int g   = tid + it * 256;
                const int row = g >> 3;
                const int kg  = g & 7;
                float v[8];
                const int ar = m0 + row;
                if (ar < M) {
                    const float4 p0 = *(const float4*)(Ap + (size_t)ar * D + kt + kg * 8);
                    const float4 p1 = *(const float4*)(Ap + (size_t)ar * D + kt + kg * 8 + 4);
                    v[0] = p0.x; v[1] = p0.y; v[2] = p0.z; v[3] = p0.w;
                    v[4] = p1.x; v[5] = p1.y; v[6] = p1.z; v[7] = p1.w;
                } else {
                    #pragma unroll
                    for (int j = 0; j < 8; ++j) v[j] = 0.f;
                }
                unsigned int hi[4], lo[4];
                #pragma unroll
                for (int j = 0; j < 4; ++j) {
                    const unsigned int ua = __float_as_uint(v[2*j]);
                    const unsigned int ub = __float_as_uint(v[2*j+1]);
                    hi[j] = (ub & 0xFFFF0000u) | (ua >> 16);
                    const float ra = v[2*j]   - __uint_as_float(ua & 0xFFFF0000u);
                    const float rb = v[2*j+1] - __uint_as_float(ub & 0xFFFF0000u);
                    lo[j] = (__float_as_uint(rb) & 0xFFFF0000u) | (__float_as_uint(ra) >> 16);
                }
                const int off = (row * BK + kg * 8) * 2;
                const int sw  = off ^ ((row & 7) << 4);
                *(u32x4*)(AhB + sw) = (u32x4){hi[0], hi[1], hi[2], hi[3]};
                *(u32x4*)(AlB + sw) = (u32x4){lo[0], lo[1], lo[2], lo[3]};
            }
            #pragma unroll
            for (int it = 0; it < 4; ++it) {
                const int g   = tid + it * 256;
                const int row = g >> 3;
                const int kg  = g & 7;
                const u32x4 wv = *(const u32x4*)(Wp + (size_t)(n0 + row) * D + kt + kg * 8);
                const int off = (row * BK + kg * 8) * 2;
                const int sw  = off ^ ((row & 7) << 4);
                *(u32x4*)(BsB + sw) = wv;
            }
            __syncthreads();
            #pragma unroll
            for (int ks = 0; ks < 2; ++ks) {
                const int kb = ks * 64 + (lane >> 4) * 16;
                bf16x8 af[4], alf[4], bfr[4];
                #pragma unroll
                for (int m = 0; m < 4; ++m) {
                    const int row = wm + m * 16 + (lane & 15);
                    const int sw  = (row * 128 + kb) ^ ((row & 7) << 4);
                    frag_cvt c1; c1.u = *(u32x4*)(AhB + sw); af[m]  = c1.h;
                    frag_cvt c2; c2.u = *(u32x4*)(AlB + sw); alf[m] = c2.h;
                }
                #pragma unroll
                for (int n = 0; n < 4; ++n) {
                    const int row = wn + n * 16 + (lane & 15);
                    const int sw  = (row * 128 + kb) ^ ((row & 7) << 4);
                    frag_cvt c; c.u = *(u32x4*)(BsB + sw); bfr[n] = c.h;
                }
                #pragma unroll
                for (int m = 0; m < 4; ++m)
                    #pragma unroll
                    for (int n = 0; n < 4; ++n) {
                        acc[m][n] = __builtin_amdgcn_mfma_f32_16x16x32_bf16(af[m],  bfr[n], acc[m][n], 0, 0, 0);
                        acc[m][n] = __builtin_amdgcn_mfma_f32_16x16x32_bf16(alf[m], bfr[n], acc[m][n], 0, 0, 0);
                    }
            }
            __syncthreads();
        }
    }
    float* Ct = C + (size_t)t * M * D;
    #pragma unroll
    for (int n = 0; n < 4; ++n) {
        const int col = n0 + wn + n * 16 + (lane & 15);
        const float bc = bias ? bias[t * D + col] : 0.f;
        #pragma unroll
        for (int m = 0; m < 4; ++m) {
            const int rb = m0 + wm + m * 16 + (lane >> 4) * 4;
            #pragma unroll
            for (int i = 0; i < 4; ++i) {
                const int r = rb + i;
                if (r < M) Ct[(size_t)r * D + col] = acc[m][n][i] + bc;
            }
        }
    }
}

// ---------------- LayerNorm, one wave per row ----------------
__global__ __launch_bounds__(256) void ln_wave_kernel(
    const float* __restrict__ in, const float* __restrict__ res,
    const float* __restrict__ g, const float* __restrict__ b,
    float* __restrict__ out, int N)
{
    const int row  = (blockIdx.x * 256 + threadIdx.x) >> 6;
    const int lane = threadIdx.x & 63;
    if (row >= 2 * N) return;
    const int t = (row >= N) ? 1 : 0;
    float4 v = *(const float4*)(in + (size_t)row * D + lane * 4);
    if (res) {
        const float4 r = *(const float4*)(res + (size_t)row * D + lane * 4);
        v.x += r.x; v.y += r.y; v.z += r.z; v.w += r.w;
    }
    float s = v.x + v.y + v.z + v.w;
    #pragma unroll
    for (int off = 32; off > 0; off >>= 1) s += __shfl_xor(s, off);
    const float mu = s * (1.0f / 256.0f);
    const float4 dl = make_float4(v.x - mu, v.y - mu, v.z - mu, v.w - mu);
    float q = dl.x * dl.x + dl.y * dl.y + dl.z * dl.z + dl.w * dl.w;
    #pragma unroll
    for (int off = 32; off > 0; off >>= 1) q += __shfl_xor(q, off);
    const float rstd = rsqrtf(q * (1.0f / 256.0f) + 1e-5f);
    const float4 gv = *(const float4*)(g + (size_t)t * D + lane * 4);
    const float4 bv = *(const float4*)(b + (size_t)t * D + lane * 4);
    float4 o;
    o.x = dl.x * rstd * gv.x + bv.x;
    o.y = dl.y * rstd * gv.y + bv.y;
    o.z = dl.z * rstd * gv.z + bv.z;
    o.w = dl.w * rstd * gv.w + bv.w;
    *(float4*)(out + (size_t)row * D + lane * 4) = o;
}

// ---------------- CSR build ----------------
__global__ void count_kernel(const int* __restrict__ e_dst, int* __restrict__ cnt,
                             int E2, int N, int E)
{
    const int i = blockIdx.x * 256 + threadIdx.x;
    if (i >= E2) return;
    const int t = i / E;
    atomicAdd(&cnt[(size_t)t * N + e_dst[i]], 1);
}

__global__ __launch_bounds__(1024) void scan_kernel(const int* __restrict__ cnt,
                                                    int* __restrict__ offs, int n)
{
    __shared__ int ts[1024];
    const int tid = threadIdx.x;
    const int chunk = (n + 1023) / 1024;
    const int b = tid * chunk;
    const int e = min(b + chunk, n);
    int s = 0;
    for (int i = b; i < e; ++i) s += cnt[i];
    ts[tid] = s;
    __syncthreads();
    for (int off = 1; off < 1024; off <<= 1) {
        const int v = (tid >= off) ? ts[tid - off] : 0;
        __syncthreads();
        ts[tid] += v;
        __syncthreads();
    }
    int base = ts[tid] - s;
    for (int i = b; i < e; ++i) { offs[i] = base; base += cnt[i]; }
    if (tid == 1023) offs[n] = ts[1023];
}

__global__ void fill_kernel(const int* __restrict__ e_src, const int* __restrict__ e_dst,
                            const int* __restrict__ offs, int* __restrict__ cur,
                            int* __restrict__ sorted, int E2, int N, int E)
{
    const int i = blockIdx.x * 256 + threadIdx.x;
    if (i >= E2) return;
    const int t = i / E;
    const int idx = t * N + e_dst[i];
    const int pos = offs[idx] + atomicAdd(&cur[idx], 1);
    sorted[pos] = e_src[i];
}

// ---------------- aggregation: one wave per (t, dst) node, gather + mean ----------------
__global__ __launch_bounds__(256) void agg_kernel(
    const float* __restrict__ h, const int* __restrict__ sorted_src,
    const int* __restrict__ offs, float* __restrict__ agg, int N)
{
    const int gw   = (blockIdx.x * 256 + threadIdx.x) >> 6;
    const int lane = threadIdx.x & 63;
    if (gw >= 2 * N) return;
    const int t = (gw >= N) ? 1 : 0;
    const int beg = offs[gw];
    const int end = offs[gw + 1];
    const float* hb = h + (size_t)t * N * D;
    float4 acc = make_float4(0.f, 0.f, 0.f, 0.f);
    for (int e = beg; e < end; ++e) {
        const int src = sorted_src[e];
        const float4 v = *(const float4*)(hb + (size_t)src * D + lane * 4);
        acc.x += v.x; acc.y += v.y; acc.z += v.z; acc.w += v.w;
    }
    const float inv = 1.0f / fmaxf((float)(end - beg), 1.0f);
    acc.x *= inv; acc.y *= inv; acc.z *= inv; acc.w *= inv;
    *(float4*)(agg + (size_t)gw * D + lane * 4) = acc;
}

// ---------------- scores ----------------
__global__ __launch_bounds__(256) void score_kernel(
    const float* __restrict__ h,
    const int* __restrict__ pos_src, const int* __restrict__ pos_dst,
    const int* __restrict__ neg_src, const int* __restrict__ neg_dst,
    float* __restrict__ out, int EP, int N)
{
    const int wid  = (blockIdx.x * 256 + threadIdx.x) >> 6;
    const int lane = threadIdx.x & 63;
    if (wid >= 2 * EP) return;
    const int kind = wid / EP;
    const int k    = wid - kind * EP;
    const int s = kind ? neg_src[k] : pos_src[k];
    const int d = kind ? neg_dst[k] : pos_dst[k];
    const float4 a = *reinterpret_cast<const float4*>(h + (size_t)s * D + lane * 4);
    const float4 b = *reinterpret_cast<const float4*>(h + ((size_t)N + d) * D + lane * 4);
    float v = a.x * b.x + a.y * b.y + a.z * b.z + a.w * b.w;
    #pragma unroll
    for (int off = 32; off > 0; off >>= 1) v += __shfl_down(v, off);
    if (lane == 0) out[wid] = v;
}

extern "C" void kernel_launch(void* const* d_in, const int* in_sizes, int n_in,
                              void* d_out, int out_size, void* d_ws, size_t ws_size,
                              hipStream_t stream)
{
    const float* x      = (const float*)d_in[0];
    const float* W_in   = (const float*)d_in[1];
    const float* b_in   = (const float*)d_in[2];
    const float* lora_A = (const float*)d_in[3];
    const float* lora_B = (const float*)d_in[4];
    const float* pn_g   = (const float*)d_in[5];
    const float* pn_b   = (const float*)d_in[6];
    const float* W_self = (const float*)d_in[7];
    const float* W_neigh= (const float*)d_in[8];
    const float* b_sage = (const float*)d_in[9];
    const float* ln_g   = (const float*)d_in[10];
    const float* ln_b   = (const float*)d_in[11];
    const float* Wv     = (const float*)d_in[12];
    const float* bvp    = (const float*)d_in[13];
    const float* Wo     = (const float*)d_in[14];
    const float* bo     = (const float*)d_in[15];
    const int* e_src    = (const int*)d_in[16];
    const int* e_dst    = (const int*)d_in[17];
    const int* pos_src  = (const int*)d_in[18];
    const int* pos_dst  = (const int*)d_in[19];
    const int* neg_src  = (const int*)d_in[20];
    const int* neg_dst  = (const int*)d_in[21];

    const int N  = in_sizes[0] / (2 * D);
    const int E  = in_sizes[16] / 2;
    const int EP = in_sizes[18];
    const size_t ND2 = (size_t)2 * N * D;
    const size_t DD2 = (size_t)2 * D * D;

    float* ws   = (float*)d_ws;
    float* h    = ws;
    float* tmp  = h   + ND2;
    float* agg  = tmp + ND2;
    int* cnt    = (int*)(agg + ND2);
    int* offs   = cnt  + (size_t)2 * N;
    int* cur    = offs + (size_t)2 * N + 1;
    int* sorted = cur  + (size_t)2 * N;
    float* wvo  = (float*)(sorted + (size_t)2 * E);
    float* bvo  = wvo + DD2;
    float* b1e  = bvo + 2 * D;
    unsigned short* win_eff = (unsigned short*)(b1e + 2 * D);
    unsigned short* ws0 = win_eff + DD2;
    unsigned short* wn0 = ws0 + DD2;
    unsigned short* ws1 = wn0 + DD2;
    unsigned short* wn1 = ws1 + DD2;

    // ---- weight precompute (all tiny) ----
    lora_fold_kernel<<<dim3(D, 1, 2), 256, 0, stream>>>(W_in, lora_A, lora_B, win_eff);
    f32_to_bf16_rn_kernel<<<((int)DD2 + 255) / 256, 256, 0, stream>>>(W_self,  ws0, (int)DD2);
    f32_to_bf16_rn_kernel<<<((int)DD2 + 255) / 256, 256, 0, stream>>>(W_neigh, wn0, (int)DD2);
    mm_nn_kernel<<<dim3(D, 1, 2), 256, 0, stream>>>(Wo, Wv, wvo, nullptr);          // W_vo = Wo.Wv
    mv_kernel<<<dim3(1, 1, 2), 256, 0, stream>>>(Wo, bvp, bo, bvo);                 // b_vo = bo + Wo.bv
    mm_nn_kernel<<<dim3(D, 1, 2), 256, 0, stream>>>(wvo, W_self  + DD2, nullptr, ws1);  // W_vo.W_self[1]
    mm_nn_kernel<<<dim3(D, 1, 2), 256, 0, stream>>>(wvo, W_neigh + DD2, nullptr, wn1);  // W_vo.W_neigh[1]
    mv_kernel<<<dim3(1, 1, 2), 256, 0, stream>>>(wvo, b_sage + 2 * D, bvo, b1e);    // b1 = b_vo + W_vo.b_sage1

    // ---- CSR build (edges shared by both layers) ----
    hipMemsetAsync(cnt, 0, (size_t)2 * N * sizeof(int), stream);
    hipMemsetAsync(cur, 0, (size_t)2 * N * sizeof(int), stream);
    count_kernel<<<(2 * E + 255) / 256, 256, 0, stream>>>(e_dst, cnt, 2 * E, N, E);
    scan_kernel<<<1, 1024, 0, stream>>>(cnt, offs, 2 * N);
    fill_kernel<<<(2 * E + 255) / 256, 256, 0, stream>>>(e_src, e_dst, offs, cur, sorted, 2 * E, N, E);

    const dim3 gblk(256);
    const dim3 ggrid((N + BM - 1) / BM, D / BN, 2);
    const int ln_grid = (2 * N + 3) / 4;

    // input projection (LoRA folded) + prenorm
    gemm_mfma_kernel<<<ggrid, gblk, 0, stream>>>(x, win_eff, nullptr, nullptr, b_in, tmp, N, 0);
    ln_wave_kernel<<<ln_grid, gblk, 0, stream>>>(tmp, nullptr, pn_g, pn_b, h, N);

    // layer 0
    agg_kernel<<<dim3((2 * N + 3) / 4, 1, 1), gblk, 0, stream>>>(h, sorted, offs, agg, N);
    gemm_mfma_kernel<<<ggrid, gblk, 0, stream>>>(h, ws0, agg, wn0, b_sage, tmp, N, 1);
    ln_wave_kernel<<<ln_grid, gblk, 0, stream>>>(tmp, nullptr, ln_g, ln_b, h, N);

    // layer 1 (Wv/Wo folded in)
    agg_kernel<<<dim3((2 * N + 3) / 4, 1, 1), gblk, 0, stream>>>(h, sorted, offs, agg, N);
    gemm_mfma_kernel<<<ggrid, gblk, 0, stream>>>(h, ws1, agg, wn1, b1e, tmp, N, 1);
    ln_wave_kernel<<<ln_grid, gblk, 0, stream>>>(tmp, h, ln_g + 2 * D, ln_b + 2 * D, h, N);

    score_kernel<<<(2 * EP + 3) / 4, gblk, 0, stream>>>(h, pos_src, pos_dst, neg_src, neg_dst,
                                                        (float*)d_out, EP, N);
}

// Round 5
// 829.116 us; speedup vs baseline: 7.0846x; 1.1819x over previous
//
#include <hip/hip_runtime.h>

#define D 256
#define BM 128
#define BN 128
#define BK 64
#define SCAN_NB 64      // phase-1/3 blocks
#define SCAN_T (SCAN_NB * 256)

typedef __attribute__((ext_vector_type(8))) short bf16x8;
typedef __attribute__((ext_vector_type(4))) float f32x4;
typedef __attribute__((ext_vector_type(4))) unsigned int u32x4;

union frag_cvt { u32x4 u; bf16x8 h; };

__device__ __forceinline__ unsigned short bf16_rn(float f) {
    const unsigned int u = __float_as_uint(f);
    return (unsigned short)((u + 0x7FFFu + ((u >> 16) & 1u)) >> 16);
}

// ---------------- fp32 -> bf16 (RN) ----------------
__global__ void f32_to_bf16_rn_kernel(const float* __restrict__ s,
                                      unsigned short* __restrict__ d, int n)
{
    const int i = blockIdx.x * 256 + threadIdx.x;
    if (i < n) d[i] = bf16_rn(s[i]);
}

// ---------------- W_eff = W + lora_B . lora_A  -> bf16 ----------------
__global__ __launch_bounds__(256) void lora_fold_kernel(
    const float* __restrict__ W, const float* __restrict__ lA,
    const float* __restrict__ lB, unsigned short* __restrict__ out)
{
    const int t = blockIdx.z, o = blockIdx.x, d = threadIdx.x;
    float acc = W[((size_t)t * D + o) * D + d];
    const float* Br = lB + ((size_t)t * D + o) * 16;
    const float* At = lA + (size_t)t * 16 * D;
    #pragma unroll
    for (int r = 0; r < 16; ++r) acc = fmaf(Br[r], At[r * D + d], acc);
    out[((size_t)t * D + o) * D + d] = bf16_rn(acc);
}

// ---------------- P[t,p,:] = sum_o X[t,p,o] * Y[t,o,:]  (NN matmul, D x D) ----------------
__global__ __launch_bounds__(256) void mm_nn_kernel(
    const float* __restrict__ X, const float* __restrict__ Y,
    float* __restrict__ Pf, unsigned short* __restrict__ Pb)
{
    const int t = blockIdx.z, p = blockIdx.x, d = threadIdx.x;
    const float* Xr = X + ((size_t)t * D + p) * D;
    const float* Yt = Y + (size_t)t * D * D;
    float acc = 0.f;
    for (int o = 0; o < D; ++o) acc = fmaf(Xr[o], Yt[(size_t)o * D + d], acc);
    if (Pf) Pf[((size_t)t * D + p) * D + d] = acc;
    if (Pb) Pb[((size_t)t * D + p) * D + d] = bf16_rn(acc);
}

// ---------------- out[t,p] = add[t,p] + sum_o M[t,p,o] * v[t,o] ----------------
__global__ __launch_bounds__(256) void mv_kernel(
    const float* __restrict__ M, const float* __restrict__ v,
    const float* __restrict__ add, float* __restrict__ out)
{
    const int t = blockIdx.z, p = threadIdx.x;
    const float* Mr = M + ((size_t)t * D + p) * D;
    const float* vr = v + (size_t)t * D;
    float acc = add[(size_t)t * D + p];
    for (int o = 0; o < D; ++o) acc = fmaf(Mr[o], vr[o], acc);
    out[(size_t)t * D + p] = acc;
}

// ---------------- MFMA GEMM: C[t] = A[t].W[t]^T (+ A2[t'].W2[t]^T) + bias ----------------
__global__ __launch_bounds__(256) void gemm_mfma_kernel(
    const float* __restrict__ A, const unsigned short* __restrict__ Wb,
    const float* __restrict__ A2, const unsigned short* __restrict__ W2b,
    const float* __restrict__ bias,
    float* __restrict__ C, int M, int swap2)
{
    const int t   = blockIdx.z;
    const int m0  = blockIdx.x * BM;
    const int n0  = blockIdx.y * BN;
    const int tid = threadIdx.x;
    const int lane = tid & 63;
    const int wid  = tid >> 6;
    const int wm = (wid >> 1) * 64;
    const int wn = (wid & 1) * 64;

    __shared__ unsigned short Ah[BM * BK];
    __shared__ unsigned short Al[BM * BK];
    __shared__ unsigned short Bs[BN * BK];
    char* AhB = (char*)Ah;
    char* AlB = (char*)Al;
    char* BsB = (char*)Bs;

    f32x4 acc[4][4];
    #pragma unroll
    for (int i = 0; i < 4; ++i)
        #pragma unroll
        for (int j = 0; j < 4; ++j)
            acc[i][j] = (f32x4){0.f, 0.f, 0.f, 0.f};

    const int npass = A2 ? 2 : 1;
    for (int pass = 0; pass < npass; ++pass) {
        const float* Ap;
        const unsigned short* Wp;
        if (pass == 0) {
            Ap = A + (size_t)t * M * D;
            Wp = Wb + (size_t)t * D * D;
        } else {
            const int t2 = swap2 ? (1 - t) : t;
            Ap = A2 + (size_t)t2 * M * D;
            Wp = W2b + (size_t)t * D * D;
        }

        for (int kt = 0; kt < D; kt += BK) {
            #pragma unroll
            for (int it = 0; it < 4; ++it) {
                const int g   = tid + it * 256;
                const int row = g >> 3;
                const int kg  = g & 7;
                float v[8];
                const int ar = m0 + row;
                if (ar < M) {
                    const float4 p0 = *(const float4*)(Ap + (size_t)ar * D + kt + kg * 8);
                    const float4 p1 = *(const float4*)(Ap + (size_t)ar * D + kt + kg * 8 + 4);
                    v[0] = p0.x; v[1] = p0.y; v[2] = p0.z; v[3] = p0.w;
                    v[4] = p1.x; v[5] = p1.y; v[6] = p1.z; v[7] = p1.w;
                } else {
                    #pragma unroll
                    for (int j = 0; j < 8; ++j) v[j] = 0.f;
                }
                unsigned int hi[4], lo[4];
                #pragma unroll
                for (int j = 0; j < 4; ++j) {
                    const unsigned int ua = __float_as_uint(v[2*j]);
                    const unsigned int ub = __float_as_uint(v[2*j+1]);
                    hi[j] = (ub & 0xFFFF0000u) | (ua >> 16);
                    const float ra = v[2*j]   - __uint_as_float(ua & 0xFFFF0000u);
                    const float rb = v[2*j+1] - __uint_as_float(ub & 0xFFFF0000u);
                    lo[j] = (__float_as_uint(rb) & 0xFFFF0000u) | (__float_as_uint(ra) >> 16);
                }
                const int off = (row * BK + kg * 8) * 2;
                const int sw  = off ^ ((row & 7) << 4);
                *(u32x4*)(AhB + sw) = (u32x4){hi[0], hi[1], hi[2], hi[3]};
                *(u32x4*)(AlB + sw) = (u32x4){lo[0], lo[1], lo[2], lo[3]};
            }
            #pragma unroll
            for (int it = 0; it < 4; ++it) {
                const int g   = tid + it * 256;
                const int row = g >> 3;
                const int kg  = g & 7;
                const u32x4 wv = *(const u32x4*)(Wp + (size_t)(n0 + row) * D + kt + kg * 8);
                const int off = (row * BK + kg * 8) * 2;
                const int sw  = off ^ ((row & 7) << 4);
                *(u32x4*)(BsB + sw) = wv;
            }
            __syncthreads();
            #pragma unroll
            for (int ks = 0; ks < 2; ++ks) {
                const int kb = ks * 64 + (lane >> 4) * 16;
                bf16x8 af[4], alf[4], bfr[4];
                #pragma unroll
                for (int m = 0; m < 4; ++m) {
                    const int row = wm + m * 16 + (lane & 15);
                    const int sw  = (row * 128 + kb) ^ ((row & 7) << 4);
                    frag_cvt c1; c1.u = *(u32x4*)(AhB + sw); af[m]  = c1.h;
                    frag_cvt c2; c2.u = *(u32x4*)(AlB + sw); alf[m] = c2.h;
                }
                #pragma unroll
                for (int n = 0; n < 4; ++n) {
                    const int row = wn + n * 16 + (lane & 15);
                    const int sw  = (row * 128 + kb) ^ ((row & 7) << 4);
                    frag_cvt c; c.u = *(u32x4*)(BsB + sw); bfr[n] = c.h;
                }
                #pragma unroll
                for (int m = 0; m < 4; ++m)
                    #pragma unroll
                    for (int n = 0; n < 4; ++n) {
                        acc[m][n] = __builtin_amdgcn_mfma_f32_16x16x32_bf16(af[m],  bfr[n], acc[m][n], 0, 0, 0);
                        acc[m][n] = __builtin_amdgcn_mfma_f32_16x16x32_bf16(alf[m], bfr[n], acc[m][n], 0, 0, 0);
                    }
            }
            __syncthreads();
        }
    }
    float* Ct = C + (size_t)t * M * D;
    #pragma unroll
    for (int n = 0; n < 4; ++n) {
        const int col = n0 + wn + n * 16 + (lane & 15);
        const float bc = bias ? bias[t * D + col] : 0.f;
        #pragma unroll
        for (int m = 0; m < 4; ++m) {
            const int rb = m0 + wm + m * 16 + (lane >> 4) * 4;
            #pragma unroll
            for (int i = 0; i < 4; ++i) {
                const int r = rb + i;
                if (r < M) Ct[(size_t)r * D + col] = acc[m][n][i] + bc;
            }
        }
    }
}

// ---------------- LayerNorm, one wave per row ----------------
__global__ __launch_bounds__(256) void ln_wave_kernel(
    const float* __restrict__ in, const float* __restrict__ res,
    const float* __restrict__ g, const float* __restrict__ b,
    float* __restrict__ out, int N)
{
    const int row  = (blockIdx.x * 256 + threadIdx.x) >> 6;
    const int lane = threadIdx.x & 63;
    if (row >= 2 * N) return;
    const int t = (row >= N) ? 1 : 0;
    float4 v = *(const float4*)(in + (size_t)row * D + lane * 4);
    if (res) {
        const float4 r = *(const float4*)(res + (size_t)row * D + lane * 4);
        v.x += r.x; v.y += r.y; v.z += r.z; v.w += r.w;
    }
    float s = v.x + v.y + v.z + v.w;
    #pragma unroll
    for (int off = 32; off > 0; off >>= 1) s += __shfl_xor(s, off);
    const float mu = s * (1.0f / 256.0f);
    const float4 dl = make_float4(v.x - mu, v.y - mu, v.z - mu, v.w - mu);
    float q = dl.x * dl.x + dl.y * dl.y + dl.z * dl.z + dl.w * dl.w;
    #pragma unroll
    for (int off = 32; off > 0; off >>= 1) q += __shfl_xor(q, off);
    const float rstd = rsqrtf(q * (1.0f / 256.0f) + 1e-5f);
    const float4 gv = *(const float4*)(g + (size_t)t * D + lane * 4);
    const float4 bv = *(const float4*)(b + (size_t)t * D + lane * 4);
    float4 o;
    o.x = dl.x * rstd * gv.x + bv.x;
    o.y = dl.y * rstd * gv.y + bv.y;
    o.z = dl.z * rstd * gv.z + bv.z;
    o.w = dl.w * rstd * gv.w + bv.w;
    *(float4*)(out + (size_t)row * D + lane * 4) = o;
}

// ---------------- CSR build ----------------
__global__ void count_kernel(const int* __restrict__ e_dst, int* __restrict__ cnt,
                             int E2, int N, int E)
{
    const int i = blockIdx.x * 256 + threadIdx.x;
    if (i >= E2) return;
    const int t = i / E;
    atomicAdd(&cnt[(size_t)t * N + e_dst[i]], 1);
}

// ---- 3-phase multi-block exclusive scan over n counts ----
__global__ __launch_bounds__(256) void scan1_kernel(const int* __restrict__ cnt,
                                                    int* __restrict__ texcl,
                                                    int* __restrict__ bsum, int n, int c)
{
    __shared__ int ts[256];
    const int tid = threadIdx.x;
    const int gt  = blockIdx.x * 256 + tid;
    const int b   = gt * c;
    const int e   = min(b + c, n);
    int s = 0;
    for (int i = b; i < e; ++i) s += cnt[i];
    ts[tid] = s;
    __syncthreads();
    #pragma unroll
    for (int off = 1; off < 256; off <<= 1) {
        const int v = (tid >= off) ? ts[tid - off] : 0;
        __syncthreads();
        ts[tid] += v;
        __syncthreads();
    }
    texcl[gt] = ts[tid] - s;                   // exclusive within block
    if (tid == 255) bsum[blockIdx.x] = ts[255];
}

__global__ __launch_bounds__(64) void scan2_kernel(int* __restrict__ bsum,
                                                   int* __restrict__ bbase,
                                                   int* __restrict__ offs, int n, int nb)
{
    const int lane = threadIdx.x;
    int v = (lane < nb) ? bsum[lane] : 0;
    int s = v;
    #pragma unroll
    for (int off = 1; off < 64; off <<= 1) {
        const int u = __shfl_up(s, off);
        if (lane >= off) s += u;
    }
    if (lane < nb) bbase[lane] = s - v;        // exclusive
    if (lane == 63) offs[n] = s;               // total
}

__global__ __launch_bounds__(256) void scan3_kernel(const int* __restrict__ cnt,
                                                    const int* __restrict__ texcl,
                                                    const int* __restrict__ bbase,
                                                    int* __restrict__ offs, int n, int c)
{
    const int tid = threadIdx.x;
    const int gt  = blockIdx.x * 256 + tid;
    const int b   = gt * c;
    const int e   = min(b + c, n);
    int base = bbase[blockIdx.x] + texcl[gt];
    for (int i = b; i < e; ++i) { offs[i] = base; base += cnt[i]; }
}

__global__ void fill_kernel(const int* __restrict__ e_src, const int* __restrict__ e_dst,
                            const int* __restrict__ offs, int* __restrict__ cur,
                            int* __restrict__ sorted, int E2, int N, int E)
{
    const int i = blockIdx.x * 256 + threadIdx.x;
    if (i >= E2) return;
    const int t = i / E;
    const int idx = t * N + e_dst[i];
    const int pos = offs[idx] + atomicAdd(&cur[idx], 1);
    sorted[pos] = e_src[i];
}

// ---------------- aggregation: one wave per (t, dst) node, gather + mean ----------------
__global__ __launch_bounds__(256) void agg_kernel(
    const float* __restrict__ h, const int* __restrict__ sorted_src,
    const int* __restrict__ offs, float* __restrict__ agg, int N)
{
    const int gw   = (blockIdx.x * 256 + threadIdx.x) >> 6;
    const int lane = threadIdx.x & 63;
    if (gw >= 2 * N) return;
    const int t = (gw >= N) ? 1 : 0;
    const int beg = offs[gw];
    const int end = offs[gw + 1];
    const float* hb = h + (size_t)t * N * D;
    float4 acc = make_float4(0.f, 0.f, 0.f, 0.f);
    for (int e = beg; e < end; ++e) {
        const int src = sorted_src[e];
        const float4 v = *(const float4*)(hb + (size_t)src * D + lane * 4);
        acc.x += v.x; acc.y += v.y; acc.z += v.z; acc.w += v.w;
    }
    const float inv = 1.0f / fmaxf((float)(end - beg), 1.0f);
    acc.x *= inv; acc.y *= inv; acc.z *= inv; acc.w *= inv;
    *(float4*)(agg + (size_t)gw * D + lane * 4) = acc;
}

// ---------------- scores ----------------
__global__ __launch_bounds__(256) void score_kernel(
    const float* __restrict__ h,
    const int* __restrict__ pos_src, const int* __restrict__ pos_dst,
    const int* __restrict__ neg_src, const int* __restrict__ neg_dst,
    float* __restrict__ out, int EP, int N)
{
    const int wid  = (blockIdx.x * 256 + threadIdx.x) >> 6;
    const int lane = threadIdx.x & 63;
    if (wid >= 2 * EP) return;
    const int kind = wid / EP;
    const int k    = wid - kind * EP;
    const int s = kind ? neg_src[k] : pos_src[k];
    const int d = kind ? neg_dst[k] : pos_dst[k];
    const float4 a = *reinterpret_cast<const float4*>(h + (size_t)s * D + lane * 4);
    const float4 b = *reinterpret_cast<const float4*>(h + ((size_t)N + d) * D + lane * 4);
    float v = a.x * b.x + a.y * b.y + a.z * b.z + a.w * b.w;
    #pragma unroll
    for (int off = 32; off > 0; off >>= 1) v += __shfl_down(v, off);
    if (lane == 0) out[wid] = v;
}

extern "C" void kernel_launch(void* const* d_in, const int* in_sizes, int n_in,
                              void* d_out, int out_size, void* d_ws, size_t ws_size,
                              hipStream_t stream)
{
    const float* x      = (const float*)d_in[0];
    const float* W_in   = (const float*)d_in[1];
    const float* b_in   = (const float*)d_in[2];
    const float* lora_A = (const float*)d_in[3];
    const float* lora_B = (const float*)d_in[4];
    const float* pn_g   = (const float*)d_in[5];
    const float* pn_b   = (const float*)d_in[6];
    const float* W_self = (const float*)d_in[7];
    const float* W_neigh= (const float*)d_in[8];
    const float* b_sage = (const float*)d_in[9];
    const float* ln_g   = (const float*)d_in[10];
    const float* ln_b   = (const float*)d_in[11];
    const float* Wv     = (const float*)d_in[12];
    const float* bvp    = (const float*)d_in[13];
    const float* Wo     = (const float*)d_in[14];
    const float* bo     = (const float*)d_in[15];
    const int* e_src    = (const int*)d_in[16];
    const int* e_dst    = (const int*)d_in[17];
    const int* pos_src  = (const int*)d_in[18];
    const int* pos_dst  = (const int*)d_in[19];
    const int* neg_src  = (const int*)d_in[20];
    const int* neg_dst  = (const int*)d_in[21];

    const int N  = in_sizes[0] / (2 * D);
    const int E  = in_sizes[16] / 2;
    const int EP = in_sizes[18];
    const size_t ND2 = (size_t)2 * N * D;
    const size_t DD2 = (size_t)2 * D * D;
    const int n2 = 2 * N;

    float* ws   = (float*)d_ws;
    float* h    = ws;
    float* tmp  = h   + ND2;
    float* agg  = tmp + ND2;
    int* cnt    = (int*)(agg + ND2);
    int* offs   = cnt  + (size_t)n2;
    int* cur    = offs + (size_t)n2 + 1;
    int* sorted = cur  + (size_t)n2;
    int* texcl  = sorted + (size_t)2 * E;   // SCAN_T
    int* bsum   = texcl + SCAN_T;           // SCAN_NB
    int* bbase  = bsum + SCAN_NB;           // SCAN_NB
    float* wvo  = (float*)(bbase + SCAN_NB);
    float* bvo  = wvo + DD2;
    float* b1e  = bvo + 2 * D;
    unsigned short* win_eff = (unsigned short*)(b1e + 2 * D);
    unsigned short* ws0 = win_eff + DD2;
    unsigned short* wn0 = ws0 + DD2;
    unsigned short* ws1 = wn0 + DD2;
    unsigned short* wn1 = ws1 + DD2;

    // ---- weight precompute (all tiny) ----
    lora_fold_kernel<<<dim3(D, 1, 2), 256, 0, stream>>>(W_in, lora_A, lora_B, win_eff);
    f32_to_bf16_rn_kernel<<<((int)DD2 + 255) / 256, 256, 0, stream>>>(W_self,  ws0, (int)DD2);
    f32_to_bf16_rn_kernel<<<((int)DD2 + 255) / 256, 256, 0, stream>>>(W_neigh, wn0, (int)DD2);
    mm_nn_kernel<<<dim3(D, 1, 2), 256, 0, stream>>>(Wo, Wv, wvo, nullptr);
    mv_kernel<<<dim3(1, 1, 2), 256, 0, stream>>>(Wo, bvp, bo, bvo);
    mm_nn_kernel<<<dim3(D, 1, 2), 256, 0, stream>>>(wvo, W_self  + DD2, nullptr, ws1);
    mm_nn_kernel<<<dim3(D, 1, 2), 256, 0, stream>>>(wvo, W_neigh + DD2, nullptr, wn1);
    mv_kernel<<<dim3(1, 1, 2), 256, 0, stream>>>(wvo, b_sage + 2 * D, bvo, b1e);

    // ---- CSR build (edges shared by both layers) ----
    hipMemsetAsync(cnt, 0, (size_t)n2 * sizeof(int), stream);
    hipMemsetAsync(cur, 0, (size_t)n2 * sizeof(int), stream);
    count_kernel<<<(2 * E + 255) / 256, 256, 0, stream>>>(e_dst, cnt, 2 * E, N, E);
    const int sc = (n2 + SCAN_T - 1) / SCAN_T;   // elems per thread
    scan1_kernel<<<SCAN_NB, 256, 0, stream>>>(cnt, texcl, bsum, n2, sc);
    scan2_kernel<<<1, 64, 0, stream>>>(bsum, bbase, offs, n2, SCAN_NB);
    scan3_kernel<<<SCAN_NB, 256, 0, stream>>>(cnt, texcl, bbase, offs, n2, sc);
    fill_kernel<<<(2 * E + 255) / 256, 256, 0, stream>>>(e_src, e_dst, offs, cur, sorted, 2 * E, N, E);

    const dim3 gblk(256);
    const dim3 ggrid((N + BM - 1) / BM, D / BN, 2);
    const int ln_grid = (2 * N + 3) / 4;

    // input projection (LoRA folded) + prenorm
    gemm_mfma_kernel<<<ggrid, gblk, 0, stream>>>(x, win_eff, nullptr, nullptr, b_in, tmp, N, 0);
    ln_wave_kernel<<<ln_grid, gblk, 0, stream>>>(tmp, nullptr, pn_g, pn_b, h, N);

    // layer 0
    agg_kernel<<<dim3((2 * N + 3) / 4, 1, 1), gblk, 0, stream>>>(h, sorted, offs, agg, N);
    gemm_mfma_kernel<<<ggrid, gblk, 0, stream>>>(h, ws0, agg, wn0, b_sage, tmp, N, 1);
    ln_wave_kernel<<<ln_grid, gblk, 0, stream>>>(tmp, nullptr, ln_g, ln_b, h, N);

    // layer 1 (Wv/Wo folded in)
    agg_kernel<<<dim3((2 * N + 3) / 4, 1, 1), gblk, 0, stream>>>(h, sorted, offs, agg, N);
    gemm_mfma_kernel<<<ggrid, gblk, 0, stream>>>(h, ws1, agg, wn1, b1e, tmp, N, 1);
    ln_wave_kernel<<<ln_grid, gblk, 0, stream>>>(tmp, h, ln_g + 2 * D, ln_b + 2 * D, h, N);

    score_kernel<<<(2 * EP + 3) / 4, gblk, 0, stream>>>(h, pos_src, pos_dst, neg_src, neg_dst,
                                                        (float*)d_out, EP, N);
}

// Round 6
// 819.140 us; speedup vs baseline: 7.1709x; 1.0122x over previous
//
#include <hip/hip_runtime.h>

#define D 256
#define BM 128
#define BN 128
#define BK 64
#define SCAN_NB 64
#define SCAN_T (SCAN_NB * 256)

typedef __attribute__((ext_vector_type(8))) short bf16x8;
typedef __attribute__((ext_vector_type(4))) float f32x4;
typedef __attribute__((ext_vector_type(4))) unsigned int u32x4;

union frag_cvt { u32x4 u; bf16x8 h; };

__device__ __forceinline__ unsigned short bf16_rn(float f) {
    const unsigned int u = __float_as_uint(f);
    return (unsigned short)((u + 0x7FFFu + ((u >> 16) & 1u)) >> 16);
}
__device__ __forceinline__ float bf16_to_f32(unsigned short s) {
    return __uint_as_float(((unsigned int)s) << 16);
}

// ---------------- fp32 -> bf16 (RN) ----------------
__global__ void f32_to_bf16_rn_kernel(const float* __restrict__ s,
                                      unsigned short* __restrict__ d, int n)
{
    const int i = blockIdx.x * 256 + threadIdx.x;
    if (i < n) d[i] = bf16_rn(s[i]);
}

// ---------------- x -> (hi trunc, lo = exact remainder trunc) bf16 planes ----------------
__global__ __launch_bounds__(256) void split_x_kernel(
    const float* __restrict__ x, unsigned short* __restrict__ hi,
    unsigned short* __restrict__ lo, size_t n4)
{
    const size_t i = (size_t)blockIdx.x * 256 + threadIdx.x;
    if (i >= n4) return;
    const float4 v = *(const float4*)(x + i * 4);
    ushort4 h4, l4;
    {
        const unsigned int u = __float_as_uint(v.x);
        h4.x = (unsigned short)(u >> 16);
        l4.x = (unsigned short)(__float_as_uint(v.x - __uint_as_float(u & 0xFFFF0000u)) >> 16);
    }
    {
        const unsigned int u = __float_as_uint(v.y);
        h4.y = (unsigned short)(u >> 16);
        l4.y = (unsigned short)(__float_as_uint(v.y - __uint_as_float(u & 0xFFFF0000u)) >> 16);
    }
    {
        const unsigned int u = __float_as_uint(v.z);
        h4.z = (unsigned short)(u >> 16);
        l4.z = (unsigned short)(__float_as_uint(v.z - __uint_as_float(u & 0xFFFF0000u)) >> 16);
    }
    {
        const unsigned int u = __float_as_uint(v.w);
        h4.w = (unsigned short)(u >> 16);
        l4.w = (unsigned short)(__float_as_uint(v.w - __uint_as_float(u & 0xFFFF0000u)) >> 16);
    }
    *(ushort4*)(hi + i * 4) = h4;
    *(ushort4*)(lo + i * 4) = l4;
}

// ---------------- W_eff = W + lora_B . lora_A  -> bf16 ----------------
__global__ __launch_bounds__(256) void lora_fold_kernel(
    const float* __restrict__ W, const float* __restrict__ lA,
    const float* __restrict__ lB, unsigned short* __restrict__ out)
{
    const int t = blockIdx.z, o = blockIdx.x, d = threadIdx.x;
    float acc = W[((size_t)t * D + o) * D + d];
    const float* Br = lB + ((size_t)t * D + o) * 16;
    const float* At = lA + (size_t)t * 16 * D;
    #pragma unroll
    for (int r = 0; r < 16; ++r) acc = fmaf(Br[r], At[r * D + d], acc);
    out[((size_t)t * D + o) * D + d] = bf16_rn(acc);
}

// ---------------- P[t,p,:] = sum_o X[t,p,o] * Y[t,o,:]  (NN matmul, D x D) ----------------
__global__ __launch_bounds__(256) void mm_nn_kernel(
    const float* __restrict__ X, const float* __restrict__ Y,
    float* __restrict__ Pf, unsigned short* __restrict__ Pb)
{
    const int t = blockIdx.z, p = blockIdx.x, d = threadIdx.x;
    const float* Xr = X + ((size_t)t * D + p) * D;
    const float* Yt = Y + (size_t)t * D * D;
    float acc = 0.f;
    for (int o = 0; o < D; ++o) acc = fmaf(Xr[o], Yt[(size_t)o * D + d], acc);
    if (Pf) Pf[((size_t)t * D + p) * D + d] = acc;
    if (Pb) Pb[((size_t)t * D + p) * D + d] = bf16_rn(acc);
}

// ---------------- out[t,p] = add[t,p] + sum_o M[t,p,o] * v[t,o] ----------------
__global__ __launch_bounds__(256) void mv_kernel(
    const float* __restrict__ M, const float* __restrict__ v,
    const float* __restrict__ add, float* __restrict__ out)
{
    const int t = blockIdx.z, p = threadIdx.x;
    const float* Mr = M + ((size_t)t * D + p) * D;
    const float* vr = v + (size_t)t * D;
    float acc = add[(size_t)t * D + p];
    for (int o = 0; o < D; ++o) acc = fmaf(Mr[o], vr[o], acc);
    out[(size_t)t * D + p] = acc;
}

// ---------------- bf16 MFMA GEMM: C[t] = A[t].W[t]^T (+ A2[t'].W2[t]^T) + bias ----------------
__global__ __launch_bounds__(256) void gemm_bf16_kernel(
    const unsigned short* __restrict__ A, const unsigned short* __restrict__ Wb,
    const unsigned short* __restrict__ A2, const unsigned short* __restrict__ W2b,
    const float* __restrict__ bias,
    float* __restrict__ C, int M, int swap2)
{
    const int t   = blockIdx.z;
    const int m0  = blockIdx.x * BM;
    const int n0  = blockIdx.y * BN;
    const int tid = threadIdx.x;
    const int lane = tid & 63;
    const int wid  = tid >> 6;
    const int wm = (wid >> 1) * 64;
    const int wn = (wid & 1) * 64;

    __shared__ unsigned short As[BM * BK];
    __shared__ unsigned short Bs[BN * BK];
    char* AsB = (char*)As;
    char* BsB = (char*)Bs;

    f32x4 acc[4][4];
    #pragma unroll
    for (int i = 0; i < 4; ++i)
        #pragma unroll
        for (int j = 0; j < 4; ++j)
            acc[i][j] = (f32x4){0.f, 0.f, 0.f, 0.f};

    const int npass = A2 ? 2 : 1;
    for (int pass = 0; pass < npass; ++pass) {
        const unsigned short* Ap;
        const unsigned short* Wp;
        if (pass == 0) {
            Ap = A + (size_t)t * M * D;
            Wp = Wb + (size_t)t * D * D;
        } else {
            const int t2 = swap2 ? (1 - t) : t;
            Ap = A2 + (size_t)t2 * M * D;
            Wp = W2b + (size_t)t * D * D;
        }

        for (int kt = 0; kt < D; kt += BK) {
            // stage A (16KB, 4 rounds) swizzled
            #pragma unroll
            for (int it = 0; it < 4; ++it) {
                const int g   = tid + it * 256;
                const int row = g >> 3;
                const int kg  = g & 7;
                const int ar  = m0 + row;
                u32x4 av = (u32x4){0u, 0u, 0u, 0u};
                if (ar < M) av = *(const u32x4*)(Ap + (size_t)ar * D + kt + kg * 8);
                const int sw = ((row * BK + kg * 8) * 2) ^ ((row & 7) << 4);
                *(u32x4*)(AsB + sw) = av;
            }
            // stage B (16KB, 4 rounds) swizzled
            #pragma unroll
            for (int it = 0; it < 4; ++it) {
                const int g   = tid + it * 256;
                const int row = g >> 3;
                const int kg  = g & 7;
                const u32x4 wv = *(const u32x4*)(Wp + (size_t)(n0 + row) * D + kt + kg * 8);
                const int sw = ((row * BK + kg * 8) * 2) ^ ((row & 7) << 4);
                *(u32x4*)(BsB + sw) = wv;
            }
            __syncthreads();
            #pragma unroll
            for (int ks = 0; ks < 2; ++ks) {
                const int kb = ks * 64 + (lane >> 4) * 16;
                bf16x8 af[4], bfr[4];
                #pragma unroll
                for (int m = 0; m < 4; ++m) {
                    const int row = wm + m * 16 + (lane & 15);
                    const int sw  = (row * 128 + kb) ^ ((row & 7) << 4);
                    frag_cvt c; c.u = *(u32x4*)(AsB + sw); af[m] = c.h;
                }
                #pragma unroll
                for (int n = 0; n < 4; ++n) {
                    const int row = wn + n * 16 + (lane & 15);
                    const int sw  = (row * 128 + kb) ^ ((row & 7) << 4);
                    frag_cvt c; c.u = *(u32x4*)(BsB + sw); bfr[n] = c.h;
                }
                #pragma unroll
                for (int m = 0; m < 4; ++m)
                    #pragma unroll
                    for (int n = 0; n < 4; ++n)
                        acc[m][n] = __builtin_amdgcn_mfma_f32_16x16x32_bf16(af[m], bfr[n], acc[m][n], 0, 0, 0);
            }
            __syncthreads();
        }
    }
    float* Ct = C + (size_t)t * M * D;
    #pragma unroll
    for (int n = 0; n < 4; ++n) {
        const int col = n0 + wn + n * 16 + (lane & 15);
        const float bc = bias ? bias[t * D + col] : 0.f;
        #pragma unroll
        for (int m = 0; m < 4; ++m) {
            const int rb = m0 + wm + m * 16 + (lane >> 4) * 4;
            #pragma unroll
            for (int i = 0; i < 4; ++i) {
                const int r = rb + i;
                if (r < M) Ct[(size_t)r * D + col] = acc[m][n][i] + bc;
            }
        }
    }
}

// ---------------- LayerNorm, one wave per row; optional bf16 copy out ----------------
__global__ __launch_bounds__(256) void ln_wave_kernel(
    const float* __restrict__ in, const float* __restrict__ res,
    const float* __restrict__ g, const float* __restrict__ b,
    float* __restrict__ out, unsigned short* __restrict__ out_bf, int N)
{
    const int row  = (blockIdx.x * 256 + threadIdx.x) >> 6;
    const int lane = threadIdx.x & 63;
    if (row >= 2 * N) return;
    const int t = (row >= N) ? 1 : 0;
    float4 v = *(const float4*)(in + (size_t)row * D + lane * 4);
    if (res) {
        const float4 r = *(const float4*)(res + (size_t)row * D + lane * 4);
        v.x += r.x; v.y += r.y; v.z += r.z; v.w += r.w;
    }
    float s = v.x + v.y + v.z + v.w;
    #pragma unroll
    for (int off = 32; off > 0; off >>= 1) s += __shfl_xor(s, off);
    const float mu = s * (1.0f / 256.0f);
    const float4 dl = make_float4(v.x - mu, v.y - mu, v.z - mu, v.w - mu);
    float q = dl.x * dl.x + dl.y * dl.y + dl.z * dl.z + dl.w * dl.w;
    #pragma unroll
    for (int off = 32; off > 0; off >>= 1) q += __shfl_xor(q, off);
    const float rstd = rsqrtf(q * (1.0f / 256.0f) + 1e-5f);
    const float4 gv = *(const float4*)(g + (size_t)t * D + lane * 4);
    const float4 bv = *(const float4*)(b + (size_t)t * D + lane * 4);
    float4 o;
    o.x = dl.x * rstd * gv.x + bv.x;
    o.y = dl.y * rstd * gv.y + bv.y;
    o.z = dl.z * rstd * gv.z + bv.z;
    o.w = dl.w * rstd * gv.w + bv.w;
    *(float4*)(out + (size_t)row * D + lane * 4) = o;
    if (out_bf) {
        ushort4 ob;
        ob.x = bf16_rn(o.x); ob.y = bf16_rn(o.y);
        ob.z = bf16_rn(o.z); ob.w = bf16_rn(o.w);
        *(ushort4*)(out_bf + (size_t)row * D + lane * 4) = ob;
    }
}

// ---------------- CSR build ----------------
__global__ void count_kernel(const int* __restrict__ e_dst, int* __restrict__ cnt,
                             int E2, int N, int E)
{
    const int i = blockIdx.x * 256 + threadIdx.x;
    if (i >= E2) return;
    const int t = i / E;
    atomicAdd(&cnt[(size_t)t * N + e_dst[i]], 1);
}

__global__ __launch_bounds__(256) void scan1_kernel(const int* __restrict__ cnt,
                                                    int* __restrict__ texcl,
                                                    int* __restrict__ bsum, int n, int c)
{
    __shared__ int ts[256];
    const int tid = threadIdx.x;
    const int gt  = blockIdx.x * 256 + tid;
    const int b   = gt * c;
    const int e   = min(b + c, n);
    int s = 0;
    for (int i = b; i < e; ++i) s += cnt[i];
    ts[tid] = s;
    __syncthreads();
    #pragma unroll
    for (int off = 1; off < 256; off <<= 1) {
        const int v = (tid >= off) ? ts[tid - off] : 0;
        __syncthreads();
        ts[tid] += v;
        __syncthreads();
    }
    texcl[gt] = ts[tid] - s;
    if (tid == 255) bsum[blockIdx.x] = ts[255];
}

__global__ __launch_bounds__(64) void scan2_kernel(int* __restrict__ bsum,
                                                   int* __restrict__ bbase,
                                                   int* __restrict__ offs, int n, int nb)
{
    const int lane = threadIdx.x;
    int v = (lane < nb) ? bsum[lane] : 0;
    int s = v;
    #pragma unroll
    for (int off = 1; off < 64; off <<= 1) {
        const int u = __shfl_up(s, off);
        if (lane >= off) s += u;
    }
    if (lane < nb) bbase[lane] = s - v;
    if (lane == 63) offs[n] = s;
}

__global__ __launch_bounds__(256) void scan3_kernel(const int* __restrict__ cnt,
                                                    const int* __restrict__ texcl,
                                                    const int* __restrict__ bbase,
                                                    int* __restrict__ offs, int n, int c)
{
    const int tid = threadIdx.x;
    const int gt  = blockIdx.x * 256 + tid;
    const int b   = gt * c;
    const int e   = min(b + c, n);
    int base = bbase[blockIdx.x] + texcl[gt];
    for (int i = b; i < e; ++i) { offs[i] = base; base += cnt[i]; }
}

__global__ void fill_kernel(const int* __restrict__ e_src, const int* __restrict__ e_dst,
                            const int* __restrict__ offs, int* __restrict__ cur,
                            int* __restrict__ sorted, int E2, int N, int E)
{
    const int i = blockIdx.x * 256 + threadIdx.x;
    if (i >= E2) return;
    const int t = i / E;
    const int idx = t * N + e_dst[i];
    const int pos = offs[idx] + atomicAdd(&cur[idx], 1);
    sorted[pos] = e_src[i];
}

// ---------------- aggregation: one wave per (t, dst) node, bf16 gather + mean -> bf16 ----------------
__global__ __launch_bounds__(256) void agg_kernel(
    const unsigned short* __restrict__ hbf, const int* __restrict__ sorted_src,
    const int* __restrict__ offs, unsigned short* __restrict__ aggbf, int N)
{
    const int gw   = (blockIdx.x * 256 + threadIdx.x) >> 6;
    const int lane = threadIdx.x & 63;
    if (gw >= 2 * N) return;
    const int t = (gw >= N) ? 1 : 0;
    const int beg = offs[gw];
    const int end = offs[gw + 1];
    const unsigned short* hb = hbf + (size_t)t * N * D;
    float4 acc = make_float4(0.f, 0.f, 0.f, 0.f);
    for (int e = beg; e < end; ++e) {
        const int src = sorted_src[e];
        const ushort4 v = *(const ushort4*)(hb + (size_t)src * D + lane * 4);
        acc.x += bf16_to_f32(v.x); acc.y += bf16_to_f32(v.y);
        acc.z += bf16_to_f32(v.z); acc.w += bf16_to_f32(v.w);
    }
    const float inv = 1.0f / fmaxf((float)(end - beg), 1.0f);
    ushort4 o;
    o.x = bf16_rn(acc.x * inv); o.y = bf16_rn(acc.y * inv);
    o.z = bf16_rn(acc.z * inv); o.w = bf16_rn(acc.w * inv);
    *(ushort4*)(aggbf + (size_t)gw * D + lane * 4) = o;
}

// ---------------- scores ----------------
__global__ __launch_bounds__(256) void score_kernel(
    const float* __restrict__ h,
    const int* __restrict__ pos_src, const int* __restrict__ pos_dst,
    const int* __restrict__ neg_src, const int* __restrict__ neg_dst,
    float* __restrict__ out, int EP, int N)
{
    const int wid  = (blockIdx.x * 256 + threadIdx.x) >> 6;
    const int lane = threadIdx.x & 63;
    if (wid >= 2 * EP) return;
    const int kind = wid / EP;
    const int k    = wid - kind * EP;
    const int s = kind ? neg_src[k] : pos_src[k];
    const int d = kind ? neg_dst[k] : pos_dst[k];
    const float4 a = *reinterpret_cast<const float4*>(h + (size_t)s * D + lane * 4);
    const float4 b = *reinterpret_cast<const float4*>(h + ((size_t)N + d) * D + lane * 4);
    float v = a.x * b.x + a.y * b.y + a.z * b.z + a.w * b.w;
    #pragma unroll
    for (int off = 32; off > 0; off >>= 1) v += __shfl_down(v, off);
    if (lane == 0) out[wid] = v;
}

extern "C" void kernel_launch(void* const* d_in, const int* in_sizes, int n_in,
                              void* d_out, int out_size, void* d_ws, size_t ws_size,
                              hipStream_t stream)
{
    const float* x      = (const float*)d_in[0];
    const float* W_in   = (const float*)d_in[1];
    const float* b_in   = (const float*)d_in[2];
    const float* lora_A = (const float*)d_in[3];
    const float* lora_B = (const float*)d_in[4];
    const float* pn_g   = (const float*)d_in[5];
    const float* pn_b   = (const float*)d_in[6];
    const float* W_self = (const float*)d_in[7];
    const float* W_neigh= (const float*)d_in[8];
    const float* b_sage = (const float*)d_in[9];
    const float* ln_g   = (const float*)d_in[10];
    const float* ln_b   = (const float*)d_in[11];
    const float* Wv     = (const float*)d_in[12];
    const float* bvp    = (const float*)d_in[13];
    const float* Wo     = (const float*)d_in[14];
    const float* bo     = (const float*)d_in[15];
    const int* e_src    = (const int*)d_in[16];
    const int* e_dst    = (const int*)d_in[17];
    const int* pos_src  = (const int*)d_in[18];
    const int* pos_dst  = (const int*)d_in[19];
    const int* neg_src  = (const int*)d_in[20];
    const int* neg_dst  = (const int*)d_in[21];

    const int N  = in_sizes[0] / (2 * D);
    const int E  = in_sizes[16] / 2;
    const int EP = in_sizes[18];
    const size_t ND2 = (size_t)2 * N * D;
    const size_t DD2 = (size_t)2 * D * D;
    const int n2 = 2 * N;

    float* ws   = (float*)d_ws;
    float* h    = ws;
    float* tmp  = h + ND2;
    unsigned short* actbf = (unsigned short*)(tmp + ND2);
    unsigned short* hbf   = actbf;          // aliases x_hi (dead after input GEMM)
    unsigned short* aggbf = actbf + ND2;    // aliases x_lo (dead after input GEMM)
    int* cnt    = (int*)(actbf + 2 * ND2);
    int* offs   = cnt  + (size_t)n2;
    int* cur    = offs + (size_t)n2 + 1;
    int* sorted = cur  + (size_t)n2;
    int* texcl  = sorted + (size_t)2 * E;
    int* bsum   = texcl + SCAN_T;
    int* bbase  = bsum + SCAN_NB;
    float* wvo  = (float*)(bbase + SCAN_NB);
    float* bvo  = wvo + DD2;
    float* b1e  = bvo + 2 * D;
    unsigned short* win_eff = (unsigned short*)(b1e + 2 * D);
    unsigned short* ws0 = win_eff + DD2;
    unsigned short* wn0 = ws0 + DD2;
    unsigned short* ws1 = wn0 + DD2;
    unsigned short* wn1 = ws1 + DD2;

    // ---- weight precompute (tiny) ----
    lora_fold_kernel<<<dim3(D, 1, 2), 256, 0, stream>>>(W_in, lora_A, lora_B, win_eff);
    f32_to_bf16_rn_kernel<<<((int)DD2 + 255) / 256, 256, 0, stream>>>(W_self,  ws0, (int)DD2);
    f32_to_bf16_rn_kernel<<<((int)DD2 + 255) / 256, 256, 0, stream>>>(W_neigh, wn0, (int)DD2);
    mm_nn_kernel<<<dim3(D, 1, 2), 256, 0, stream>>>(Wo, Wv, wvo, nullptr);
    mv_kernel<<<dim3(1, 1, 2), 256, 0, stream>>>(Wo, bvp, bo, bvo);
    mm_nn_kernel<<<dim3(D, 1, 2), 256, 0, stream>>>(wvo, W_self  + DD2, nullptr, ws1);
    mm_nn_kernel<<<dim3(D, 1, 2), 256, 0, stream>>>(wvo, W_neigh + DD2, nullptr, wn1);
    mv_kernel<<<dim3(1, 1, 2), 256, 0, stream>>>(wvo, b_sage + 2 * D, bvo, b1e);

    // ---- CSR build (edges shared by both layers) ----
    hipMemsetAsync(cnt, 0, (size_t)n2 * sizeof(int), stream);
    hipMemsetAsync(cur, 0, (size_t)n2 * sizeof(int), stream);
    count_kernel<<<(2 * E + 255) / 256, 256, 0, stream>>>(e_dst, cnt, 2 * E, N, E);
    const int sc = (n2 + SCAN_T - 1) / SCAN_T;
    scan1_kernel<<<SCAN_NB, 256, 0, stream>>>(cnt, texcl, bsum, n2, sc);
    scan2_kernel<<<1, 64, 0, stream>>>(bsum, bbase, offs, n2, SCAN_NB);
    scan3_kernel<<<SCAN_NB, 256, 0, stream>>>(cnt, texcl, bbase, offs, n2, sc);
    fill_kernel<<<(2 * E + 255) / 256, 256, 0, stream>>>(e_src, e_dst, offs, cur, sorted, 2 * E, N, E);

    const dim3 gblk(256);
    const dim3 ggrid((N + BM - 1) / BM, D / BN, 2);
    const int ln_grid = (2 * N + 3) / 4;

    // ---- input projection: exact fp32 via hi/lo split planes ----
    unsigned short* x_hi = hbf;     // alias
    unsigned short* x_lo = aggbf;   // alias
    split_x_kernel<<<(int)((ND2 / 4 + 255) / 256), gblk, 0, stream>>>(x, x_hi, x_lo, ND2 / 4);
    gemm_bf16_kernel<<<ggrid, gblk, 0, stream>>>(x_hi, win_eff, x_lo, win_eff, b_in, tmp, N, 0);
    ln_wave_kernel<<<ln_grid, gblk, 0, stream>>>(tmp, nullptr, pn_g, pn_b, h, hbf, N);

    // ---- layer 0 ----
    agg_kernel<<<dim3((2 * N + 3) / 4, 1, 1), gblk, 0, stream>>>(hbf, sorted, offs, aggbf, N);
    gemm_bf16_kernel<<<ggrid, gblk, 0, stream>>>(hbf, ws0, aggbf, wn0, b_sage, tmp, N, 1);
    ln_wave_kernel<<<ln_grid, gblk, 0, stream>>>(tmp, nullptr, ln_g, ln_b, h, hbf, N);

    // ---- layer 1 (Wv/Wo folded) ----
    agg_kernel<<<dim3((2 * N + 3) / 4, 1, 1), gblk, 0, stream>>>(hbf, sorted, offs, aggbf, N);
    gemm_bf16_kernel<<<ggrid, gblk, 0, stream>>>(hbf, ws1, aggbf, wn1, b1e, tmp, N, 1);
    ln_wave_kernel<<<ln_grid, gblk, 0, stream>>>(tmp, h, ln_g + 2 * D, ln_b + 2 * D, h, nullptr, N);

    score_kernel<<<(2 * EP + 3) / 4, gblk, 0, stream>>>(h, pos_src, pos_dst, neg_src, neg_dst,
                                                        (float*)d_out, EP, N);
}